// Round 2
// baseline (294.159 us; speedup 1.0000x reference)
//
#include <hip/hip_runtime.h>

#define WS_ALIGN(x) (((x) + 255) & ~(size_t)255)

__global__ void zero_i32(int* __restrict__ p, int n) {
    int i = blockIdx.x * blockDim.x + threadIdx.x;
    if (i < n) p[i] = 0;
}

__global__ void deg_kernel(const int* __restrict__ dst, int* __restrict__ deg, int E) {
    int e = blockIdx.x * blockDim.x + threadIdx.x;
    if (e < E) atomicAdd(&deg[dst[e]], 1);
}

// Block-level inclusive scan helper pattern (Hillis-Steele, 256 threads)
__global__ void scan1_kernel(const int* __restrict__ deg, int* __restrict__ bsum, int N) {
    __shared__ int tmp[256];
    int tid = threadIdx.x;
    int i = blockIdx.x * 256 + tid;
    int v = (i < N) ? deg[i] : 0;
    tmp[tid] = v;
    __syncthreads();
    for (int off = 1; off < 256; off <<= 1) {
        int t = (tid >= off) ? tmp[tid - off] : 0;
        __syncthreads();
        tmp[tid] += t;
        __syncthreads();
    }
    if (tid == 255) bsum[blockIdx.x] = tmp[255];
}

__global__ void scan2_kernel(const int* __restrict__ bsum, int* __restrict__ boff, int nb) {
    // nb <= 256 required (N <= 65536)
    __shared__ int tmp[256];
    int tid = threadIdx.x;
    int v = (tid < nb) ? bsum[tid] : 0;
    tmp[tid] = v;
    __syncthreads();
    for (int off = 1; off < 256; off <<= 1) {
        int t = (tid >= off) ? tmp[tid - off] : 0;
        __syncthreads();
        tmp[tid] += t;
        __syncthreads();
    }
    if (tid < nb) boff[tid] = tmp[tid] - v;  // exclusive
}

__global__ void scan3_kernel(const int* __restrict__ deg, const int* __restrict__ boff,
                             int* __restrict__ rowptr, int* __restrict__ cursor,
                             float* __restrict__ dis, int N) {
    __shared__ int tmp[256];
    int tid = threadIdx.x;
    int i = blockIdx.x * 256 + tid;
    int v = (i < N) ? deg[i] : 0;
    tmp[tid] = v;
    __syncthreads();
    for (int off = 1; off < 256; off <<= 1) {
        int t = (tid >= off) ? tmp[tid - off] : 0;
        __syncthreads();
        tmp[tid] += t;
        __syncthreads();
    }
    int excl = tmp[tid] - v + boff[blockIdx.x];
    if (i < N) {
        rowptr[i] = excl;
        cursor[i] = excl;
        dis[i] = rsqrtf((float)(v < 1 ? 1 : v));
        if (i == N - 1) rowptr[N] = excl + v;
    }
}

__global__ void fill_kernel(const int* __restrict__ src, const int* __restrict__ dst,
                            const float* __restrict__ ew, const float* __restrict__ dis,
                            int* __restrict__ cursor, int2* __restrict__ csr, int E) {
    int e = blockIdx.x * blockDim.x + threadIdx.x;
    if (e >= E) return;
    int s = src[e], d = dst[e];
    float nm = dis[s] * ew[e] * dis[d];
    int pos = atomicAdd(&cursor[d], 1);
    csr[pos] = make_int2(s, __float_as_int(nm));
}

// One wave per destination node; lane owns 2 features; both batches per wave.
__global__ __launch_bounds__(256) void agg_kernel(const float* __restrict__ x,
                                                  const int* __restrict__ rowptr,
                                                  const int2* __restrict__ csr,
                                                  float* __restrict__ out, int N) {
    int node = blockIdx.x * 4 + (threadIdx.x >> 6);
    if (node >= N) return;
    int lane = threadIdx.x & 63;
    int beg = rowptr[node], end = rowptr[node + 1];
    float2 a0 = make_float2(0.f, 0.f), a1 = make_float2(0.f, 0.f);
    const float* xb1 = x + (size_t)N * 128;
    for (int j = beg; j < end; ++j) {
        int2 p = csr[j];
        float nm = __int_as_float(p.y);
        float2 v0 = *(const float2*)(x   + (size_t)p.x * 128 + lane * 2);
        float2 v1 = *(const float2*)(xb1 + (size_t)p.x * 128 + lane * 2);
        a0.x = fmaf(v0.x, nm, a0.x);
        a0.y = fmaf(v0.y, nm, a0.y);
        a1.x = fmaf(v1.x, nm, a1.x);
        a1.y = fmaf(v1.y, nm, a1.y);
    }
    *(float2*)(out + (size_t)node * 128 + lane * 2) = a0;
    *(float2*)(out + (size_t)(N + node) * 128 + lane * 2) = a1;
}

// In-place [M x 128] @ W^T + b.  W transposed into LDS (pad 129),
// A staged in 128x17 k-chunks, 8x8 register tile per thread.
__global__ __launch_bounds__(256) void linear_kernel(float* __restrict__ io,
                                                     const float* __restrict__ W,
                                                     const float* __restrict__ bias, int M) {
    __shared__ float Wt[128 * 129];
    __shared__ float As[128 * 17];
    int tid = threadIdx.x;
    for (int idx = tid; idx < 128 * 128; idx += 256) {
        int o = idx >> 7, k = idx & 127;
        Wt[k * 129 + o] = W[idx];
    }
    int tx = tid & 15, ty = tid >> 4;
    float bs[8];
#pragma unroll
    for (int j = 0; j < 8; ++j) bs[j] = bias[tx + 16 * j];
    float acc[8][8];
#pragma unroll
    for (int i = 0; i < 8; ++i)
#pragma unroll
        for (int j = 0; j < 8; ++j) acc[i][j] = 0.f;
    int m0 = blockIdx.x * 128;
    __syncthreads();
    for (int kk = 0; kk < 128; kk += 16) {
#pragma unroll
        for (int i = 0; i < 8; ++i) {
            int r = ty + i * 16;
            int m = m0 + r;
            float v = (m < M) ? io[(size_t)m * 128 + kk + tx] : 0.f;
            As[r * 17 + tx] = v;
        }
        __syncthreads();
#pragma unroll
        for (int k = 0; k < 16; ++k) {
            float a[8], w[8];
#pragma unroll
            for (int i = 0; i < 8; ++i) a[i] = As[(ty + 16 * i) * 17 + k];
#pragma unroll
            for (int j = 0; j < 8; ++j) w[j] = Wt[(kk + k) * 129 + tx + 16 * j];
#pragma unroll
            for (int i = 0; i < 8; ++i)
#pragma unroll
                for (int j = 0; j < 8; ++j) acc[i][j] = fmaf(a[i], w[j], acc[i][j]);
        }
        __syncthreads();
    }
#pragma unroll
    for (int i = 0; i < 8; ++i) {
        int m = m0 + ty + 16 * i;
        if (m < M) {
#pragma unroll
            for (int j = 0; j < 8; ++j)
                io[(size_t)m * 128 + tx + 16 * j] = acc[i][j] + bs[j];
        }
    }
}

extern "C" void kernel_launch(void* const* d_in, const int* in_sizes, int n_in,
                              void* d_out, int out_size, void* d_ws, size_t ws_size,
                              hipStream_t stream) {
    const float* x    = (const float*)d_in[0];
    const int*   eidx = (const int*)d_in[1];   // [2][E] flat: src then dst
    const float* ew   = (const float*)d_in[2];
    const float* W    = (const float*)d_in[3];
    const float* bias = (const float*)d_in[4];
    float* out = (float*)d_out;

    const int E = in_sizes[2];                 // edge_weight count
    const int N = in_sizes[0] / 256;           // B=2, F=128 -> N = size/(2*128)
    const int nb = (N + 255) / 256;            // scan blocks (must be <= 256)

    const int* src = eidx;
    const int* dst = eidx + E;

    char* w = (char*)d_ws;
    int*   deg    = (int*)w;   w += WS_ALIGN((size_t)N * 4);
    int*   rowptr = (int*)w;   w += WS_ALIGN((size_t)(N + 1) * 4);
    int*   cursor = (int*)w;   w += WS_ALIGN((size_t)N * 4);
    float* dis    = (float*)w; w += WS_ALIGN((size_t)N * 4);
    int*   bsum   = (int*)w;   w += WS_ALIGN((size_t)nb * 4);
    int*   boff   = (int*)w;   w += WS_ALIGN((size_t)nb * 4);
    int2*  csr    = (int2*)w;  w += WS_ALIGN((size_t)E * 8);

    hipLaunchKernelGGL(zero_i32,    dim3((N + 255) / 256), dim3(256), 0, stream, deg, N);
    hipLaunchKernelGGL(deg_kernel,  dim3((E + 255) / 256), dim3(256), 0, stream, dst, deg, E);
    hipLaunchKernelGGL(scan1_kernel, dim3(nb), dim3(256), 0, stream, deg, bsum, N);
    hipLaunchKernelGGL(scan2_kernel, dim3(1),  dim3(256), 0, stream, bsum, boff, nb);
    hipLaunchKernelGGL(scan3_kernel, dim3(nb), dim3(256), 0, stream, deg, boff, rowptr, cursor, dis, N);
    hipLaunchKernelGGL(fill_kernel, dim3((E + 255) / 256), dim3(256), 0, stream,
                       src, dst, ew, dis, cursor, csr, E);
    hipLaunchKernelGGL(agg_kernel,  dim3((N + 3) / 4), dim3(256), 0, stream, x, rowptr, csr, out, N);
    hipLaunchKernelGGL(linear_kernel, dim3((2 * N + 127) / 128), dim3(256), 0, stream,
                       out, W, bias, 2 * N);
}

// Round 3
// 292.491 us; speedup vs baseline: 1.0057x; 1.0057x over previous
//
#include <hip/hip_runtime.h>

#define WS_ALIGN(x) (((x) + 255) & ~(size_t)255)

__global__ void deg_kernel(const int* __restrict__ dst, int* __restrict__ deg, int E) {
    int e = blockIdx.x * blockDim.x + threadIdx.x;
    if (e < E) atomicAdd(&deg[dst[e]], 1);
}

// Block-level inclusive scan helper pattern (Hillis-Steele, 256 threads)
__global__ void scan1_kernel(const int* __restrict__ deg, int* __restrict__ bsum, int N) {
    __shared__ int tmp[256];
    int tid = threadIdx.x;
    int i = blockIdx.x * 256 + tid;
    int v = (i < N) ? deg[i] : 0;
    tmp[tid] = v;
    __syncthreads();
    for (int off = 1; off < 256; off <<= 1) {
        int t = (tid >= off) ? tmp[tid - off] : 0;
        __syncthreads();
        tmp[tid] += t;
        __syncthreads();
    }
    if (tid == 255) bsum[blockIdx.x] = tmp[255];
}

__global__ void scan2_kernel(const int* __restrict__ bsum, int* __restrict__ boff, int nb) {
    // nb <= 256 required (N <= 65536)
    __shared__ int tmp[256];
    int tid = threadIdx.x;
    int v = (tid < nb) ? bsum[tid] : 0;
    tmp[tid] = v;
    __syncthreads();
    for (int off = 1; off < 256; off <<= 1) {
        int t = (tid >= off) ? tmp[tid - off] : 0;
        __syncthreads();
        tmp[tid] += t;
        __syncthreads();
    }
    if (tid < nb) boff[tid] = tmp[tid] - v;  // exclusive
}

__global__ void scan3_kernel(const int* __restrict__ deg, const int* __restrict__ boff,
                             int* __restrict__ rowptr, int* __restrict__ cursor,
                             float* __restrict__ dis, int N) {
    __shared__ int tmp[256];
    int tid = threadIdx.x;
    int i = blockIdx.x * 256 + tid;
    int v = (i < N) ? deg[i] : 0;
    tmp[tid] = v;
    __syncthreads();
    for (int off = 1; off < 256; off <<= 1) {
        int t = (tid >= off) ? tmp[tid - off] : 0;
        __syncthreads();
        tmp[tid] += t;
        __syncthreads();
    }
    int excl = tmp[tid] - v + boff[blockIdx.x];
    if (i < N) {
        rowptr[i] = excl;
        cursor[i] = excl;
        dis[i] = rsqrtf((float)(v < 1 ? 1 : v));
        if (i == N - 1) rowptr[N] = excl + v;
    }
}

__global__ void fill_kernel(const int* __restrict__ src, const int* __restrict__ dst,
                            const float* __restrict__ ew, const float* __restrict__ dis,
                            int* __restrict__ cursor, int2* __restrict__ csr, int E) {
    int e = blockIdx.x * blockDim.x + threadIdx.x;
    if (e >= E) return;
    int s = src[e], d = dst[e];
    float nm = dis[s] * ew[e] * dis[d];
    int pos = atomicAdd(&cursor[d], 1);
    csr[pos] = make_int2(s, __float_as_int(nm));
}

// One wave per destination node. Half-wave 0 = batch 0, half-wave 1 = batch 1;
// lane owns 4 consecutive features (float4). CSR entries preloaded 64-wide and
// shuffle-broadcast; gathers issued in groups of 8 for MLP.
__global__ __launch_bounds__(256) void agg_kernel(const float* __restrict__ x,
                                                  const int* __restrict__ rowptr,
                                                  const int2* __restrict__ csr,
                                                  float* __restrict__ out, int N) {
    int node = blockIdx.x * 4 + (threadIdx.x >> 6);
    if (node >= N) return;
    int lane = threadIdx.x & 63;
    int half = lane >> 5;                 // which batch this half-wave handles
    int col = (lane & 31) * 4;            // float4 column
    const float* xb = x + (size_t)half * N * 128 + col;
    int beg = rowptr[node], end = rowptr[node + 1];
    float4 acc = make_float4(0.f, 0.f, 0.f, 0.f);
    for (int base = beg; base < end; base += 64) {
        int cnt = end - base;
        if (cnt > 64) cnt = 64;
        int2 p = make_int2(0, 0);
        if (lane < cnt) p = csr[base + lane];
        for (int j0 = 0; j0 < cnt; j0 += 8) {
            int m = cnt - j0;             // wave-uniform
            if (m > 8) m = 8;
            float4 v[8];
            float nm[8];
#pragma unroll
            for (int j = 0; j < 8; ++j) {
                if (j < m) {
                    int s = __shfl(p.x, j0 + j);
                    nm[j] = __int_as_float(__shfl(p.y, j0 + j));
                    v[j] = *(const float4*)(xb + (size_t)s * 128);
                }
            }
#pragma unroll
            for (int j = 0; j < 8; ++j) {
                if (j < m) {
                    acc.x = fmaf(v[j].x, nm[j], acc.x);
                    acc.y = fmaf(v[j].y, nm[j], acc.y);
                    acc.z = fmaf(v[j].z, nm[j], acc.z);
                    acc.w = fmaf(v[j].w, nm[j], acc.w);
                }
            }
        }
    }
    *(float4*)(out + (size_t)half * N * 128 + (size_t)node * 128 + col) = acc;
}

// In-place [M x 128] @ W^T + b.  W transposed into LDS (pad 129),
// A staged in 128x17 k-chunks, 8x8 register tile per thread.
__global__ __launch_bounds__(256) void linear_kernel(float* __restrict__ io,
                                                     const float* __restrict__ W,
                                                     const float* __restrict__ bias, int M) {
    __shared__ float Wt[128 * 129];
    __shared__ float As[128 * 17];
    int tid = threadIdx.x;
    for (int idx = tid; idx < 128 * 128; idx += 256) {
        int o = idx >> 7, k = idx & 127;
        Wt[k * 129 + o] = W[idx];
    }
    int tx = tid & 15, ty = tid >> 4;
    float bs[8];
#pragma unroll
    for (int j = 0; j < 8; ++j) bs[j] = bias[tx + 16 * j];
    float acc[8][8];
#pragma unroll
    for (int i = 0; i < 8; ++i)
#pragma unroll
        for (int j = 0; j < 8; ++j) acc[i][j] = 0.f;
    int m0 = blockIdx.x * 128;
    __syncthreads();
    for (int kk = 0; kk < 128; kk += 16) {
#pragma unroll
        for (int i = 0; i < 8; ++i) {
            int r = ty + i * 16;
            int m = m0 + r;
            float v = (m < M) ? io[(size_t)m * 128 + kk + tx] : 0.f;
            As[r * 17 + tx] = v;
        }
        __syncthreads();
#pragma unroll
        for (int k = 0; k < 16; ++k) {
            float a[8], w[8];
#pragma unroll
            for (int i = 0; i < 8; ++i) a[i] = As[(ty + 16 * i) * 17 + k];
#pragma unroll
            for (int j = 0; j < 8; ++j) w[j] = Wt[(kk + k) * 129 + tx + 16 * j];
#pragma unroll
            for (int i = 0; i < 8; ++i)
#pragma unroll
                for (int j = 0; j < 8; ++j) acc[i][j] = fmaf(a[i], w[j], acc[i][j]);
        }
        __syncthreads();
    }
#pragma unroll
    for (int i = 0; i < 8; ++i) {
        int m = m0 + ty + 16 * i;
        if (m < M) {
#pragma unroll
            for (int j = 0; j < 8; ++j)
                io[(size_t)m * 128 + tx + 16 * j] = acc[i][j] + bs[j];
        }
    }
}

extern "C" void kernel_launch(void* const* d_in, const int* in_sizes, int n_in,
                              void* d_out, int out_size, void* d_ws, size_t ws_size,
                              hipStream_t stream) {
    const float* x    = (const float*)d_in[0];
    const int*   eidx = (const int*)d_in[1];   // [2][E] flat: src then dst
    const float* ew   = (const float*)d_in[2];
    const float* W    = (const float*)d_in[3];
    const float* bias = (const float*)d_in[4];
    float* out = (float*)d_out;

    const int E = in_sizes[2];                 // edge_weight count
    const int N = in_sizes[0] / 256;           // B=2, F=128 -> N = size/(2*128)
    const int nb = (N + 255) / 256;            // scan blocks (must be <= 256)

    const int* src = eidx;
    const int* dst = eidx + E;

    char* w = (char*)d_ws;
    int*   deg    = (int*)w;   w += WS_ALIGN((size_t)N * 4);
    int*   rowptr = (int*)w;   w += WS_ALIGN((size_t)(N + 1) * 4);
    int*   cursor = (int*)w;   w += WS_ALIGN((size_t)N * 4);
    float* dis    = (float*)w; w += WS_ALIGN((size_t)N * 4);
    int*   bsum   = (int*)w;   w += WS_ALIGN((size_t)nb * 4);
    int*   boff   = (int*)w;   w += WS_ALIGN((size_t)nb * 4);
    int2*  csr    = (int2*)w;  w += WS_ALIGN((size_t)E * 8);

    hipMemsetAsync(deg, 0, (size_t)N * 4, stream);
    hipLaunchKernelGGL(deg_kernel,  dim3((E + 255) / 256), dim3(256), 0, stream, dst, deg, E);
    hipLaunchKernelGGL(scan1_kernel, dim3(nb), dim3(256), 0, stream, deg, bsum, N);
    hipLaunchKernelGGL(scan2_kernel, dim3(1),  dim3(256), 0, stream, bsum, boff, nb);
    hipLaunchKernelGGL(scan3_kernel, dim3(nb), dim3(256), 0, stream, deg, boff, rowptr, cursor, dis, N);
    hipLaunchKernelGGL(fill_kernel, dim3((E + 255) / 256), dim3(256), 0, stream,
                       src, dst, ew, dis, cursor, csr, E);
    hipLaunchKernelGGL(agg_kernel,  dim3((N + 3) / 4), dim3(256), 0, stream, x, rowptr, csr, out, N);
    hipLaunchKernelGGL(linear_kernel, dim3((2 * N + 127) / 128), dim3(256), 0, stream,
                       out, W, bias, 2 * N);
}

// Round 4
// 258.602 us; speedup vs baseline: 1.1375x; 1.1310x over previous
//
#include <hip/hip_runtime.h>

typedef unsigned int u32;
typedef unsigned short u16;

#define WS_ALIGN(x) (((x) + 255) & ~(size_t)255)

__device__ inline u16 f2bf(float f) {
    u32 u = __float_as_uint(f);
    u32 r = (u + 0x7fffu + ((u >> 16) & 1u)) >> 16;   // RNE
    return (u16)r;
}

// x: [2][N][128] f32  ->  xh: [N][2][128] bf16 (one 512B row per node)
__global__ void tobf16_kernel(const float* __restrict__ x, uint2* __restrict__ xh, int N) {
    int t = blockIdx.x * 256 + threadIdx.x;      // over N*32 float4-groups
    if (t >= N * 32) return;
    int b = blockIdx.y;
    int r = t >> 5, c4 = t & 31;
    float4 v = *(const float4*)(x + ((size_t)b * N + r) * 128 + c4 * 4);
    u32 lo = (u32)f2bf(v.x) | ((u32)f2bf(v.y) << 16);
    u32 hi = (u32)f2bf(v.z) | ((u32)f2bf(v.w) << 16);
    xh[(size_t)r * 64 + b * 32 + c4] = make_uint2(lo, hi);
}

__global__ void deg_kernel(const int* __restrict__ dst, int* __restrict__ deg, int E) {
    int e = blockIdx.x * blockDim.x + threadIdx.x;
    if (e < E) atomicAdd(&deg[dst[e]], 1);
}

// Block-level inclusive scan (Hillis-Steele, 256 threads)
__global__ void scan1_kernel(const int* __restrict__ deg, int* __restrict__ bsum, int N) {
    __shared__ int tmp[256];
    int tid = threadIdx.x;
    int i = blockIdx.x * 256 + tid;
    int v = (i < N) ? deg[i] : 0;
    tmp[tid] = v;
    __syncthreads();
    for (int off = 1; off < 256; off <<= 1) {
        int t = (tid >= off) ? tmp[tid - off] : 0;
        __syncthreads();
        tmp[tid] += t;
        __syncthreads();
    }
    if (tid == 255) bsum[blockIdx.x] = tmp[255];
}

__global__ void scan2_kernel(const int* __restrict__ bsum, int* __restrict__ boff, int nb) {
    // nb <= 256 required
    __shared__ int tmp[256];
    int tid = threadIdx.x;
    int v = (tid < nb) ? bsum[tid] : 0;
    tmp[tid] = v;
    __syncthreads();
    for (int off = 1; off < 256; off <<= 1) {
        int t = (tid >= off) ? tmp[tid - off] : 0;
        __syncthreads();
        tmp[tid] += t;
        __syncthreads();
    }
    if (tid < nb) boff[tid] = tmp[tid] - v;  // exclusive
}

__global__ void scan3_kernel(const int* __restrict__ deg, const int* __restrict__ boff,
                             int* __restrict__ rowptr, int* __restrict__ cursor,
                             float* __restrict__ dis, int N) {
    __shared__ int tmp[256];
    int tid = threadIdx.x;
    int i = blockIdx.x * 256 + tid;
    int v = (i < N) ? deg[i] : 0;
    tmp[tid] = v;
    __syncthreads();
    for (int off = 1; off < 256; off <<= 1) {
        int t = (tid >= off) ? tmp[tid - off] : 0;
        __syncthreads();
        tmp[tid] += t;
        __syncthreads();
    }
    int excl = tmp[tid] - v + boff[blockIdx.x];
    if (i < N) {
        rowptr[i] = excl;
        cursor[i] = excl;
        dis[i] = rsqrtf((float)(v < 1 ? 1 : v));
        if (i == N - 1) rowptr[N] = excl + v;
    }
}

__global__ void fill_kernel(const int* __restrict__ src, const int* __restrict__ dst,
                            const float* __restrict__ ew, const float* __restrict__ dis,
                            int* __restrict__ cursor, int2* __restrict__ csr, int E) {
    int e = blockIdx.x * blockDim.x + threadIdx.x;
    if (e >= E) return;
    int s = src[e], d = dst[e];
    float nm = dis[s] * ew[e] * dis[d];
    int pos = atomicAdd(&cursor[d], 1);
    csr[pos] = make_int2(s, __float_as_int(nm));
}

// One wave per destination node. xh row = 512B (both batches, bf16).
// Lane l: batch = l>>5, features col=(l&31)*4 (one uint2 = 4 bf16 per lane).
// CSR entries preloaded 64-wide + shuffle-broadcast; gathers in groups of 8.
__global__ __launch_bounds__(256) void agg_kernel(const uint2* __restrict__ xh,
                                                  const int* __restrict__ rowptr,
                                                  const int2* __restrict__ csr,
                                                  float* __restrict__ out, int N) {
    int node = blockIdx.x * 4 + (threadIdx.x >> 6);
    if (node >= N) return;
    int lane = threadIdx.x & 63;
    const uint2* xb = xh + lane;
    int beg = rowptr[node], end = rowptr[node + 1];
    float4 acc = make_float4(0.f, 0.f, 0.f, 0.f);
    for (int base = beg; base < end; base += 64) {
        int cnt = end - base;
        if (cnt > 64) cnt = 64;
        int2 p = make_int2(0, 0);
        if (lane < cnt) p = csr[base + lane];
        for (int j0 = 0; j0 < cnt; j0 += 8) {
            int m = cnt - j0;             // wave-uniform
            if (m > 8) m = 8;
            uint2 q[8];
            float nm[8];
#pragma unroll
            for (int j = 0; j < 8; ++j) {
                if (j < m) {
                    int s = __shfl(p.x, j0 + j);
                    nm[j] = __int_as_float(__shfl(p.y, j0 + j));
                    q[j] = xb[(size_t)s * 64];
                }
            }
#pragma unroll
            for (int j = 0; j < 8; ++j) {
                if (j < m) {
                    acc.x = fmaf(__uint_as_float(q[j].x << 16), nm[j], acc.x);
                    acc.y = fmaf(__uint_as_float(q[j].x & 0xffff0000u), nm[j], acc.y);
                    acc.z = fmaf(__uint_as_float(q[j].y << 16), nm[j], acc.z);
                    acc.w = fmaf(__uint_as_float(q[j].y & 0xffff0000u), nm[j], acc.w);
                }
            }
        }
    }
    int half = lane >> 5, col = (lane & 31) * 4;
    *(float4*)(out + (size_t)half * N * 128 + (size_t)node * 128 + col) = acc;
}

// In-place [M x 128] @ W^T + b.  W transposed into LDS (pad 129),
// A staged in 128x17 k-chunks, 8x8 register tile per thread.
__global__ __launch_bounds__(256) void linear_kernel(float* __restrict__ io,
                                                     const float* __restrict__ W,
                                                     const float* __restrict__ bias, int M) {
    __shared__ float Wt[128 * 129];
    __shared__ float As[128 * 17];
    int tid = threadIdx.x;
    for (int idx = tid; idx < 128 * 128; idx += 256) {
        int o = idx >> 7, k = idx & 127;
        Wt[k * 129 + o] = W[idx];
    }
    int tx = tid & 15, ty = tid >> 4;
    float bs[8];
#pragma unroll
    for (int j = 0; j < 8; ++j) bs[j] = bias[tx + 16 * j];
    float acc[8][8];
#pragma unroll
    for (int i = 0; i < 8; ++i)
#pragma unroll
        for (int j = 0; j < 8; ++j) acc[i][j] = 0.f;
    int m0 = blockIdx.x * 128;
    __syncthreads();
    for (int kk = 0; kk < 128; kk += 16) {
#pragma unroll
        for (int i = 0; i < 8; ++i) {
            int r = ty + i * 16;
            int m = m0 + r;
            float v = (m < M) ? io[(size_t)m * 128 + kk + tx] : 0.f;
            As[r * 17 + tx] = v;
        }
        __syncthreads();
#pragma unroll
        for (int k = 0; k < 16; ++k) {
            float a[8], w[8];
#pragma unroll
            for (int i = 0; i < 8; ++i) a[i] = As[(ty + 16 * i) * 17 + k];
#pragma unroll
            for (int j = 0; j < 8; ++j) w[j] = Wt[(kk + k) * 129 + tx + 16 * j];
#pragma unroll
            for (int i = 0; i < 8; ++i)
#pragma unroll
                for (int j = 0; j < 8; ++j) acc[i][j] = fmaf(a[i], w[j], acc[i][j]);
        }
        __syncthreads();
    }
#pragma unroll
    for (int i = 0; i < 8; ++i) {
        int m = m0 + ty + 16 * i;
        if (m < M) {
#pragma unroll
            for (int j = 0; j < 8; ++j)
                io[(size_t)m * 128 + tx + 16 * j] = acc[i][j] + bs[j];
        }
    }
}

extern "C" void kernel_launch(void* const* d_in, const int* in_sizes, int n_in,
                              void* d_out, int out_size, void* d_ws, size_t ws_size,
                              hipStream_t stream) {
    const float* x    = (const float*)d_in[0];
    const int*   eidx = (const int*)d_in[1];   // [2][E] flat: src then dst
    const float* ew   = (const float*)d_in[2];
    const float* W    = (const float*)d_in[3];
    const float* bias = (const float*)d_in[4];
    float* out = (float*)d_out;

    const int E = in_sizes[2];                 // edge_weight count
    const int N = in_sizes[0] / 256;           // B=2, F=128 -> N = size/(2*128)
    const int nb = (N + 255) / 256;            // scan blocks (must be <= 256)

    const int* src = eidx;
    const int* dst = eidx + E;

    char* w = (char*)d_ws;
    int*   deg    = (int*)w;   w += WS_ALIGN((size_t)N * 4);
    int*   rowptr = (int*)w;   w += WS_ALIGN((size_t)(N + 1) * 4);
    int*   cursor = (int*)w;   w += WS_ALIGN((size_t)N * 4);
    float* dis    = (float*)w; w += WS_ALIGN((size_t)N * 4);
    int*   bsum   = (int*)w;   w += WS_ALIGN((size_t)nb * 4);
    int*   boff   = (int*)w;   w += WS_ALIGN((size_t)nb * 4);
    int2*  csr    = (int2*)w;  w += WS_ALIGN((size_t)E * 8);
    uint2* xh     = (uint2*)w; w += WS_ALIGN((size_t)N * 512);  // [N][64] uint2

    hipMemsetAsync(deg, 0, (size_t)N * 4, stream);
    hipLaunchKernelGGL(tobf16_kernel, dim3((N * 32 + 255) / 256, 2), dim3(256), 0, stream,
                       x, xh, N);
    hipLaunchKernelGGL(deg_kernel,  dim3((E + 255) / 256), dim3(256), 0, stream, dst, deg, E);
    hipLaunchKernelGGL(scan1_kernel, dim3(nb), dim3(256), 0, stream, deg, bsum, N);
    hipLaunchKernelGGL(scan2_kernel, dim3(1),  dim3(256), 0, stream, bsum, boff, nb);
    hipLaunchKernelGGL(scan3_kernel, dim3(nb), dim3(256), 0, stream, deg, boff, rowptr, cursor, dis, N);
    hipLaunchKernelGGL(fill_kernel, dim3((E + 255) / 256), dim3(256), 0, stream,
                       src, dst, ew, dis, cursor, csr, E);
    hipLaunchKernelGGL(agg_kernel,  dim3((N + 3) / 4), dim3(256), 0, stream, xh, rowptr, csr, out, N);
    hipLaunchKernelGGL(linear_kernel, dim3((2 * N + 127) / 128), dim3(256), 0, stream,
                       out, W, bias, 2 * N);
}

// Round 7
// 217.499 us; speedup vs baseline: 1.3525x; 1.1890x over previous
//
#include <hip/hip_runtime.h>

typedef unsigned int u32;
typedef unsigned short u16;
typedef __attribute__((ext_vector_type(8))) short bf16x8;
typedef __attribute__((ext_vector_type(4))) float f32x4;

#define WS_ALIGN(x) (((x) + 255) & ~(size_t)255)

__device__ inline u16 f2bf(float f) {
    u32 u = __float_as_uint(f);
    u32 r = (u + 0x7fffu + ((u >> 16) & 1u)) >> 16;   // RNE
    return (u16)r;
}

// x: [2][N][128] f32  ->  xh: [N][2][128] bf16 (one 512B row per node)
__global__ void tobf16_kernel(const float* __restrict__ x, uint2* __restrict__ xh, int N) {
    int t = blockIdx.x * 256 + threadIdx.x;      // over N*32 float4-groups
    if (t >= N * 32) return;
    int b = blockIdx.y;
    int r = t >> 5, c4 = t & 31;
    float4 v = *(const float4*)(x + ((size_t)b * N + r) * 128 + c4 * 4);
    u32 lo = (u32)f2bf(v.x) | ((u32)f2bf(v.y) << 16);
    u32 hi = (u32)f2bf(v.z) | ((u32)f2bf(v.w) << 16);
    xh[(size_t)r * 64 + b * 32 + c4] = make_uint2(lo, hi);
}

// W: [128][128] f32 row-major -> Wh bf16 same layout
__global__ void wtobf16_kernel(const float* __restrict__ W, uint2* __restrict__ Wh) {
    int t = blockIdx.x * 256 + threadIdx.x;      // 4096 float4-groups
    if (t >= 4096) return;
    float4 v = ((const float4*)W)[t];
    Wh[t] = make_uint2((u32)f2bf(v.x) | ((u32)f2bf(v.y) << 16),
                       (u32)f2bf(v.z) | ((u32)f2bf(v.w) << 16));
}

__global__ void deg_kernel(const int* __restrict__ dst, int* __restrict__ deg, int E) {
    int e = blockIdx.x * blockDim.x + threadIdx.x;
    if (e < E) atomicAdd(&deg[dst[e]], 1);
}

// Block-level inclusive scan (Hillis-Steele, 256 threads)
__global__ void scan1_kernel(const int* __restrict__ deg, int* __restrict__ bsum, int N) {
    __shared__ int tmp[256];
    int tid = threadIdx.x;
    int i = blockIdx.x * 256 + tid;
    int v = (i < N) ? deg[i] : 0;
    tmp[tid] = v;
    __syncthreads();
    for (int off = 1; off < 256; off <<= 1) {
        int t = (tid >= off) ? tmp[tid - off] : 0;
        __syncthreads();
        tmp[tid] += t;
        __syncthreads();
    }
    if (tid == 255) bsum[blockIdx.x] = tmp[255];
}

__global__ void scan2_kernel(const int* __restrict__ bsum, int* __restrict__ boff, int nb) {
    // nb <= 256 required
    __shared__ int tmp[256];
    int tid = threadIdx.x;
    int v = (tid < nb) ? bsum[tid] : 0;
    tmp[tid] = v;
    __syncthreads();
    for (int off = 1; off < 256; off <<= 1) {
        int t = (tid >= off) ? tmp[tid - off] : 0;
        __syncthreads();
        tmp[tid] += t;
        __syncthreads();
    }
    if (tid < nb) boff[tid] = tmp[tid] - v;  // exclusive
}

__global__ void scan3_kernel(const int* __restrict__ deg, const int* __restrict__ boff,
                             int* __restrict__ rowptr, int* __restrict__ cursor,
                             float* __restrict__ dis, int N) {
    __shared__ int tmp[256];
    int tid = threadIdx.x;
    int i = blockIdx.x * 256 + tid;
    int v = (i < N) ? deg[i] : 0;
    tmp[tid] = v;
    __syncthreads();
    for (int off = 1; off < 256; off <<= 1) {
        int t = (tid >= off) ? tmp[tid - off] : 0;
        __syncthreads();
        tmp[tid] += t;
        __syncthreads();
    }
    int excl = tmp[tid] - v + boff[blockIdx.x];
    if (i < N) {
        rowptr[i] = excl;
        cursor[i] = excl;
        dis[i] = rsqrtf((float)(v < 1 ? 1 : v));
        if (i == N - 1) rowptr[N] = excl + v;
    }
}

__global__ void fill_kernel(const int* __restrict__ src, const int* __restrict__ dst,
                            const float* __restrict__ ew, const float* __restrict__ dis,
                            int* __restrict__ cursor, int2* __restrict__ csr, int E) {
    int e = blockIdx.x * blockDim.x + threadIdx.x;
    if (e >= E) return;
    int s = src[e], d = dst[e];
    float nm = dis[s] * ew[e] * dis[d];
    int pos = atomicAdd(&cursor[d], 1);
    csr[pos] = make_int2(s, __float_as_int(nm));
}

// One wave per destination node. xh row = 512B (both batches, bf16).
// Lane l: batch = l>>5, col=(l&31)*4 (one uint2 = 4 bf16 per lane).
// CSR entries preloaded 64-wide + shuffle-broadcast; gathers in groups of 8.
// Output: fp32 out[2][N][128] (float4 per lane).
__global__ __launch_bounds__(256) void agg_kernel(const uint2* __restrict__ xh,
                                                  const int* __restrict__ rowptr,
                                                  const int2* __restrict__ csr,
                                                  float* __restrict__ out, int N) {
    int node = blockIdx.x * 4 + (threadIdx.x >> 6);
    if (node >= N) return;
    int lane = threadIdx.x & 63;
    const uint2* xb = xh + lane;
    int beg = rowptr[node], end = rowptr[node + 1];
    float4 acc = make_float4(0.f, 0.f, 0.f, 0.f);
    for (int base = beg; base < end; base += 64) {
        int cnt = end - base;
        if (cnt > 64) cnt = 64;
        int2 p = make_int2(0, 0);
        if (lane < cnt) p = csr[base + lane];
        for (int j0 = 0; j0 < cnt; j0 += 8) {
            int m = cnt - j0;             // wave-uniform
            if (m > 8) m = 8;
            uint2 q[8];
            float nm[8];
#pragma unroll
            for (int j = 0; j < 8; ++j) {
                if (j < m) {
                    int s = __shfl(p.x, j0 + j);
                    nm[j] = __int_as_float(__shfl(p.y, j0 + j));
                    q[j] = xb[(size_t)s * 64];
                }
            }
#pragma unroll
            for (int j = 0; j < 8; ++j) {
                if (j < m) {
                    acc.x = fmaf(__uint_as_float(q[j].x << 16), nm[j], acc.x);
                    acc.y = fmaf(__uint_as_float(q[j].x & 0xffff0000u), nm[j], acc.y);
                    acc.z = fmaf(__uint_as_float(q[j].y << 16), nm[j], acc.z);
                    acc.w = fmaf(__uint_as_float(q[j].y & 0xffff0000u), nm[j], acc.w);
                }
            }
        }
    }
    int half = lane >> 5, col = (lane & 31) * 4;
    *(float4*)(out + (size_t)half * N * 128 + (size_t)node * 128 + col) = acc;
}

// In-place io[M][128] = bf16(io[M][128]) @ Wh^T + bias (fp32 result).
// One wave per 16 rows; wave reads ONLY its own 16 rows (fp32), converts to
// bf16 in registers, MFMAs vs bf16 W rows, writes the same 16 rows.
// Lockstep within the wave orders all A-loads before any store -> in-place safe.
// A frag: row m=r0+(lane&15), k = kt*32 + (lane>>4)*8 + j
// B frag: col n=ct*16+(lane&15) -> Wh row n, same k map (k-permutation cancels)
// D frag (verified m89): col = lane&15, row = (lane>>4)*4 + reg.
__global__ __launch_bounds__(256) void linear_mfma_kernel(float* __restrict__ io,
                                                          const u16* __restrict__ Wh,
                                                          const float* __restrict__ bias,
                                                          int M) {
    int w = blockIdx.x * 4 + (threadIdx.x >> 6);
    int r0 = w * 16;
    if (r0 >= M) return;
    int lane = threadIdx.x & 63;
    int l15 = lane & 15, g = lane >> 4;

    int arow = r0 + l15;
    if (arow >= M) arow = M - 1;           // safety (M%16==0 in practice)
    const float* ap = io + (size_t)arow * 128 + g * 8;
    bf16x8 a[4];
#pragma unroll
    for (int kt = 0; kt < 4; ++kt) {
        float4 u0 = *(const float4*)(ap + kt * 32);
        float4 u1 = *(const float4*)(ap + kt * 32 + 4);
        bf16x8 t;
        t[0] = (short)f2bf(u0.x); t[1] = (short)f2bf(u0.y);
        t[2] = (short)f2bf(u0.z); t[3] = (short)f2bf(u0.w);
        t[4] = (short)f2bf(u1.x); t[5] = (short)f2bf(u1.y);
        t[6] = (short)f2bf(u1.z); t[7] = (short)f2bf(u1.w);
        a[kt] = t;
    }

    float res[8][4];
#pragma unroll
    for (int ct = 0; ct < 8; ++ct) {
        const u16* wp = Wh + (size_t)(ct * 16 + l15) * 128 + g * 8;
        f32x4 acc = {0.f, 0.f, 0.f, 0.f};
#pragma unroll
        for (int kt = 0; kt < 4; ++kt) {
            bf16x8 b = *(const bf16x8*)(wp + kt * 32);
            acc = __builtin_amdgcn_mfma_f32_16x16x32_bf16(a[kt], b, acc, 0, 0, 0);
        }
        float bv = bias[ct * 16 + l15];
#pragma unroll
        for (int reg = 0; reg < 4; ++reg) res[ct][reg] = acc[reg] + bv;
    }
    // stores after all MFMAs (data-dependent on all a[] loads anyway)
#pragma unroll
    for (int ct = 0; ct < 8; ++ct)
#pragma unroll
        for (int reg = 0; reg < 4; ++reg) {
            int m = r0 + g * 4 + reg;
            if (m < M)
                io[(size_t)m * 128 + ct * 16 + l15] = res[ct][reg];
        }
}

extern "C" void kernel_launch(void* const* d_in, const int* in_sizes, int n_in,
                              void* d_out, int out_size, void* d_ws, size_t ws_size,
                              hipStream_t stream) {
    const float* x    = (const float*)d_in[0];
    const int*   eidx = (const int*)d_in[1];   // [2][E] flat: src then dst
    const float* ew   = (const float*)d_in[2];
    const float* W    = (const float*)d_in[3];
    const float* bias = (const float*)d_in[4];
    float* out = (float*)d_out;

    const int E = in_sizes[2];                 // edge_weight count
    const int N = in_sizes[0] / 256;           // B=2, F=128 -> N = size/(2*128)
    const int M = 2 * N;
    const int nb = (N + 255) / 256;            // scan blocks (must be <= 256)

    const int* src = eidx;
    const int* dst = eidx + E;

    // ws footprint ~32.1 MB (csr 6.4 + xh 25.6 + misc) — round-3-proven envelope.
    char* w = (char*)d_ws;
    int*   deg    = (int*)w;   w += WS_ALIGN((size_t)N * 4);
    int*   rowptr = (int*)w;   w += WS_ALIGN((size_t)(N + 1) * 4);
    int*   cursor = (int*)w;   w += WS_ALIGN((size_t)N * 4);
    float* dis    = (float*)w; w += WS_ALIGN((size_t)N * 4);
    int*   bsum   = (int*)w;   w += WS_ALIGN((size_t)nb * 4);
    int*   boff   = (int*)w;   w += WS_ALIGN((size_t)nb * 4);
    int2*  csr    = (int2*)w;  w += WS_ALIGN((size_t)E * 8);
    uint2* xh     = (uint2*)w; w += WS_ALIGN((size_t)N * 512);      // [N][64] uint2
    uint2* Wh     = (uint2*)w; w += WS_ALIGN((size_t)128 * 128 * 2);

    hipMemsetAsync(deg, 0, (size_t)N * 4, stream);
    hipLaunchKernelGGL(tobf16_kernel, dim3((N * 32 + 255) / 256, 2), dim3(256), 0, stream,
                       x, xh, N);
    hipLaunchKernelGGL(wtobf16_kernel, dim3(16), dim3(256), 0, stream, W, Wh);
    hipLaunchKernelGGL(deg_kernel,  dim3((E + 255) / 256), dim3(256), 0, stream, dst, deg, E);
    hipLaunchKernelGGL(scan1_kernel, dim3(nb), dim3(256), 0, stream, deg, bsum, N);
    hipLaunchKernelGGL(scan2_kernel, dim3(1),  dim3(256), 0, stream, bsum, boff, nb);
    hipLaunchKernelGGL(scan3_kernel, dim3(nb), dim3(256), 0, stream, deg, boff, rowptr, cursor, dis, N);
    hipLaunchKernelGGL(fill_kernel, dim3((E + 255) / 256), dim3(256), 0, stream,
                       src, dst, ew, dis, cursor, csr, E);
    hipLaunchKernelGGL(agg_kernel,  dim3((N + 3) / 4), dim3(256), 0, stream, xh, rowptr, csr, out, N);
    int waves = (M + 15) / 16;
    hipLaunchKernelGGL(linear_mfma_kernel, dim3((waves + 3) / 4), dim3(256), 0, stream,
                       out, (const u16*)Wh, bias, M);
}

// Round 9
// 205.151 us; speedup vs baseline: 1.4339x; 1.0602x over previous
//
#include <hip/hip_runtime.h>

typedef unsigned int u32;
typedef unsigned short u16;
typedef __attribute__((ext_vector_type(8))) short bf16x8;
typedef __attribute__((ext_vector_type(4))) float f32x4;

#define WS_ALIGN(x) (((x) + 255) & ~(size_t)255)

__device__ inline u16 f2bf(float f) {
    u32 u = __float_as_uint(f);
    u32 r = (u + 0x7fffu + ((u >> 16) & 1u)) >> 16;   // RNE
    return (u16)r;
}

// x: [2][N][128] f32  ->  xh: [N][2][128] bf16 (one 512B row per node)
__global__ void tobf16_kernel(const float* __restrict__ x, uint2* __restrict__ xh, int N) {
    int t = blockIdx.x * 256 + threadIdx.x;      // over N*32 float4-groups
    if (t >= N * 32) return;
    int b = blockIdx.y;
    int r = t >> 5, c4 = t & 31;
    float4 v = *(const float4*)(x + ((size_t)b * N + r) * 128 + c4 * 4);
    u32 lo = (u32)f2bf(v.x) | ((u32)f2bf(v.y) << 16);
    u32 hi = (u32)f2bf(v.z) | ((u32)f2bf(v.w) << 16);
    xh[(size_t)r * 64 + b * 32 + c4] = make_uint2(lo, hi);
}

// W: [128][128] f32 row-major -> Wh bf16 same layout
__global__ void wtobf16_kernel(const float* __restrict__ W, uint2* __restrict__ Wh) {
    int t = blockIdx.x * 256 + threadIdx.x;      // 4096 float4-groups
    if (t >= 4096) return;
    float4 v = ((const float4*)W)[t];
    Wh[t] = make_uint2((u32)f2bf(v.x) | ((u32)f2bf(v.y) << 16),
                       (u32)f2bf(v.z) | ((u32)f2bf(v.w) << 16));
}

__global__ void deg_kernel(const int* __restrict__ dst, int* __restrict__ deg, int E) {
    int e = blockIdx.x * blockDim.x + threadIdx.x;
    if (e < E) atomicAdd(&deg[dst[e]], 1);
}

// Block scan: per-block sums (Hillis-Steele, 256 threads)
__global__ void scan1_kernel(const int* __restrict__ deg, int* __restrict__ bsum, int N) {
    __shared__ int tmp[256];
    int tid = threadIdx.x;
    int i = blockIdx.x * 256 + tid;
    int v = (i < N) ? deg[i] : 0;
    tmp[tid] = v;
    __syncthreads();
    for (int off = 1; off < 256; off <<= 1) {
        int t = (tid >= off) ? tmp[tid - off] : 0;
        __syncthreads();
        tmp[tid] += t;
        __syncthreads();
    }
    if (tid == 255) bsum[blockIdx.x] = tmp[255];
}

// scan3: each block re-scans bsum (nb<=256) in LDS for its offset, then
// finishes rowptr/cursor/dis. (scan2 merged in.)
__global__ void scan3_kernel(const int* __restrict__ deg, const int* __restrict__ bsum,
                             int* __restrict__ rowptr, int* __restrict__ cursor,
                             float* __restrict__ dis, int N, int nb) {
    __shared__ int tmp[256];
    __shared__ int bs[256];
    int tid = threadIdx.x;
    int bv = (tid < nb) ? bsum[tid] : 0;
    bs[tid] = bv;
    __syncthreads();
    for (int off = 1; off < 256; off <<= 1) {
        int t = (tid >= off) ? bs[tid - off] : 0;
        __syncthreads();
        bs[tid] += t;
        __syncthreads();
    }
    // bs[i] = inclusive sum; block offset = exclusive = bs[blockIdx.x] - bsum[blockIdx.x]
    int boff = bs[blockIdx.x] - ((blockIdx.x < nb) ? bsum[blockIdx.x] : 0);
    int i = blockIdx.x * 256 + tid;
    int v = (i < N) ? deg[i] : 0;
    tmp[tid] = v;
    __syncthreads();
    for (int off = 1; off < 256; off <<= 1) {
        int t = (tid >= off) ? tmp[tid - off] : 0;
        __syncthreads();
        tmp[tid] += t;
        __syncthreads();
    }
    int excl = tmp[tid] - v + boff;
    if (i < N) {
        rowptr[i] = excl;
        cursor[i] = excl;
        dis[i] = rsqrtf((float)(v < 1 ? 1 : v));
        if (i == N - 1) rowptr[N] = excl + v;
    }
}

__global__ void fill_kernel(const int* __restrict__ src, const int* __restrict__ dst,
                            const float* __restrict__ ew, const float* __restrict__ dis,
                            int* __restrict__ cursor, int2* __restrict__ csr, int E) {
    int e = blockIdx.x * blockDim.x + threadIdx.x;
    if (e >= E) return;
    int s = src[e], d = dst[e];
    float nm = dis[s] * ew[e] * dis[d];
    int pos = atomicAdd(&cursor[d], 1);
    csr[pos] = make_int2(s, __float_as_int(nm));
}

// Fused aggregate + linear. 512 threads = 8 waves; wave w aggregates node
// blk*8+w (both batches; lane: batch=l>>5, cols=(l&31)*4, uint2 gathers of
// bf16 xh rows), writes bf16 rows to LDS [16][128] (XOR-swizzled), then wave w
// computes output cols w*16..w*16+15 for all 16 rows via mfma_f32_16x16x32_bf16
// (A from LDS, B from bf16 W rows; identical A/B k-maps cancel the HW k-perm).
// D frag (verified m89): col = lane&15, row = (lane>>4)*4 + reg.
__global__ __launch_bounds__(512) void agg_linear_kernel(const uint2* __restrict__ xh,
                                                         const int* __restrict__ rowptr,
                                                         const int2* __restrict__ csr,
                                                         const u16* __restrict__ Wh,
                                                         const float* __restrict__ bias,
                                                         float* __restrict__ out, int N) {
    __shared__ uint2 lds[16 * 32];   // 16 rows x 32 uint2 (4KB), swizzled
    int w = threadIdx.x >> 6;        // wave 0..7
    int lane = threadIdx.x & 63;
    int node = blockIdx.x * 8 + w;
    bool active = node < N;

    // ---- aggregation (identical inner loop to round-7 agg) ----
    float4 acc = make_float4(0.f, 0.f, 0.f, 0.f);
    if (active) {
        const uint2* xb = xh + lane;
        int beg = rowptr[node], end = rowptr[node + 1];
        for (int base = beg; base < end; base += 64) {
            int cnt = end - base;
            if (cnt > 64) cnt = 64;
            int2 p = make_int2(0, 0);
            if (lane < cnt) p = csr[base + lane];
            for (int j0 = 0; j0 < cnt; j0 += 8) {
                int m = cnt - j0;             // wave-uniform
                if (m > 8) m = 8;
                uint2 q[8];
                float nm[8];
#pragma unroll
                for (int j = 0; j < 8; ++j) {
                    if (j < m) {
                        int s = __shfl(p.x, j0 + j);
                        nm[j] = __int_as_float(__shfl(p.y, j0 + j));
                        q[j] = xb[(size_t)s * 64];
                    }
                }
#pragma unroll
                for (int j = 0; j < 8; ++j) {
                    if (j < m) {
                        acc.x = fmaf(__uint_as_float(q[j].x << 16), nm[j], acc.x);
                        acc.y = fmaf(__uint_as_float(q[j].x & 0xffff0000u), nm[j], acc.y);
                        acc.z = fmaf(__uint_as_float(q[j].y << 16), nm[j], acc.z);
                        acc.w = fmaf(__uint_as_float(q[j].y & 0xffff0000u), nm[j], acc.w);
                    }
                }
            }
        }
    }
    // LDS row r = half*8 + w; chunk c = lane&31 (4 bf16). Swizzle idx ^= (r&7)<<1.
    {
        int half = lane >> 5, c = lane & 31;
        int r = half * 8 + w;
        u32 lo = (u32)f2bf(acc.x) | ((u32)f2bf(acc.y) << 16);
        u32 hi = (u32)f2bf(acc.z) | ((u32)f2bf(acc.w) << 16);
        lds[r * 32 + (c ^ ((r & 7) << 1))] = make_uint2(lo, hi);
    }
    __syncthreads();

    // ---- MFMA: wave w -> output cols w*16 .. w*16+15 ----
    int l15 = lane & 15, g = lane >> 4;
    bf16x8 a[4];
#pragma unroll
    for (int kt = 0; kt < 4; ++kt) {
        int c0 = (g * 2 + kt * 8) ^ ((l15 & 7) << 1);   // even (both XOR terms even)
        a[kt] = *(const bf16x8*)&lds[l15 * 32 + c0];
    }
    const u16* wp = Wh + (size_t)(w * 16 + l15) * 128 + g * 8;
    f32x4 dacc = {0.f, 0.f, 0.f, 0.f};
#pragma unroll
    for (int kt = 0; kt < 4; ++kt) {
        bf16x8 b = *(const bf16x8*)(wp + kt * 32);
        dacc = __builtin_amdgcn_mfma_f32_16x16x32_bf16(a[kt], b, dacc, 0, 0, 0);
    }
    float bv = bias[w * 16 + l15];
#pragma unroll
    for (int reg = 0; reg < 4; ++reg) {
        int r = g * 4 + reg;                  // D row
        int n2 = blockIdx.x * 8 + (r & 7);    // node of this row
        if (n2 < N) {
            out[((size_t)(r >> 3) * N + n2) * 128 + w * 16 + l15] = dacc[reg] + bv;
        }
    }
}

extern "C" void kernel_launch(void* const* d_in, const int* in_sizes, int n_in,
                              void* d_out, int out_size, void* d_ws, size_t ws_size,
                              hipStream_t stream) {
    const float* x    = (const float*)d_in[0];
    const int*   eidx = (const int*)d_in[1];   // [2][E] flat: src then dst
    const float* ew   = (const float*)d_in[2];
    const float* W    = (const float*)d_in[3];
    const float* bias = (const float*)d_in[4];
    float* out = (float*)d_out;

    const int E = in_sizes[2];                 // edge_weight count
    const int N = in_sizes[0] / 256;           // B=2, F=128 -> N = size/(2*128)
    const int nb = (N + 255) / 256;            // scan blocks (must be <= 256)

    const int* src = eidx;
    const int* dst = eidx + E;

    // ws footprint ~32.1 MB — round-3-proven envelope. DO NOT GROW (round-6 overflow).
    char* w = (char*)d_ws;
    int*   deg    = (int*)w;   w += WS_ALIGN((size_t)N * 4);
    int*   rowptr = (int*)w;   w += WS_ALIGN((size_t)(N + 1) * 4);
    int*   cursor = (int*)w;   w += WS_ALIGN((size_t)N * 4);
    float* dis    = (float*)w; w += WS_ALIGN((size_t)N * 4);
    int*   bsum   = (int*)w;   w += WS_ALIGN((size_t)nb * 4);
    int2*  csr    = (int2*)w;  w += WS_ALIGN((size_t)E * 8);
    uint2* xh     = (uint2*)w; w += WS_ALIGN((size_t)N * 512);      // [N][64] uint2
    uint2* Wh     = (uint2*)w; w += WS_ALIGN((size_t)128 * 128 * 2);

    hipMemsetAsync(deg, 0, (size_t)N * 4, stream);
    hipLaunchKernelGGL(tobf16_kernel, dim3((N * 32 + 255) / 256, 2), dim3(256), 0, stream,
                       x, xh, N);
    hipLaunchKernelGGL(wtobf16_kernel, dim3(16), dim3(256), 0, stream, W, Wh);
    hipLaunchKernelGGL(deg_kernel,  dim3((E + 255) / 256), dim3(256), 0, stream, dst, deg, E);
    hipLaunchKernelGGL(scan1_kernel, dim3(nb), dim3(256), 0, stream, deg, bsum, N);
    hipLaunchKernelGGL(scan3_kernel, dim3(nb), dim3(256), 0, stream, deg, bsum, rowptr, cursor, dis, N, nb);
    hipLaunchKernelGGL(fill_kernel, dim3((E + 255) / 256), dim3(256), 0, stream,
                       src, dst, ew, dis, cursor, csr, E);
    hipLaunchKernelGGL(agg_linear_kernel, dim3((N + 7) / 8), dim3(512), 0, stream,
                       xh, rowptr, csr, (const u16*)Wh, bias, out, N);
}

// Round 10
// 197.249 us; speedup vs baseline: 1.4913x; 1.0401x over previous
//
#include <hip/hip_runtime.h>

typedef unsigned int u32;
typedef unsigned short u16;
typedef __attribute__((ext_vector_type(8))) short bf16x8;
typedef __attribute__((ext_vector_type(4))) float f32x4;

#define WS_ALIGN(x) (((x) + 255) & ~(size_t)255)

__device__ inline u16 f2bf(float f) {
    u32 u = __float_as_uint(f);
    u32 r = (u + 0x7fffu + ((u >> 16) & 1u)) >> 16;   // RNE
    return (u16)r;
}

// Fused: zero deg[N]  +  W f32 -> Wh bf16 (4096 uint2 chunks)
__global__ void prep_kernel(const float* __restrict__ W, uint2* __restrict__ Wh,
                            int* __restrict__ deg, int N) {
    int t = blockIdx.x * 256 + threadIdx.x;
    if (t < N) deg[t] = 0;
    if (t < 4096) {
        float4 v = ((const float4*)W)[t];
        Wh[t] = make_uint2((u32)f2bf(v.x) | ((u32)f2bf(v.y) << 16),
                           (u32)f2bf(v.z) | ((u32)f2bf(v.w) << 16));
    }
}

// Y = X @ W^T computed BEFORE aggregation (linearity: Â(X)W^T = Â(XW^T)).
// One wave = 16 nodes of batch b (blockIdx.y). Swapped operands:
// A = W rows (D row = feature), B = x rows (D col = node) -> reg-packed stores.
// A frag: Wh row (ct*16+l15), k = kt*32 + g*8 + j
// B frag: x row (r0+l15) fp32 -> bf16, same k map (k-perm cancels; HW-validated r7/r9)
// D (verified m89): col = lane&15 (node), row = g*4+reg (feature-in-chunk)
// Store: yh[node][b][feature] bf16, uint2 per (ct) = 4 features.
__global__ __launch_bounds__(256) void gemm_yh_kernel(const float* __restrict__ x,
                                                      const u16* __restrict__ Wh,
                                                      u16* __restrict__ yh, int N) {
    int wv = blockIdx.x * 4 + (threadIdx.x >> 6);
    int r0 = wv * 16;
    if (r0 >= N) return;
    int b = blockIdx.y;
    int lane = threadIdx.x & 63;
    int l15 = lane & 15, g = lane >> 4;

    int xrow = r0 + l15;
    if (xrow >= N) xrow = N - 1;              // safe clamp (store is guarded)
    const float* xp = x + ((size_t)b * N + xrow) * 128 + g * 8;
    bf16x8 xb[4];
#pragma unroll
    for (int kt = 0; kt < 4; ++kt) {
        float4 u0 = *(const float4*)(xp + kt * 32);
        float4 u1 = *(const float4*)(xp + kt * 32 + 4);
        bf16x8 t;
        t[0] = (short)f2bf(u0.x); t[1] = (short)f2bf(u0.y);
        t[2] = (short)f2bf(u0.z); t[3] = (short)f2bf(u0.w);
        t[4] = (short)f2bf(u1.x); t[5] = (short)f2bf(u1.y);
        t[6] = (short)f2bf(u1.z); t[7] = (short)f2bf(u1.w);
        xb[kt] = t;
    }

    int node = r0 + l15;
    u16* yp = yh + (size_t)node * 256 + b * 128 + g * 4;
#pragma unroll
    for (int ct = 0; ct < 8; ++ct) {
        const u16* wp = Wh + (size_t)(ct * 16 + l15) * 128 + g * 8;
        f32x4 acc = {0.f, 0.f, 0.f, 0.f};
#pragma unroll
        for (int kt = 0; kt < 4; ++kt) {
            bf16x8 wfrag = *(const bf16x8*)(wp + kt * 32);
            acc = __builtin_amdgcn_mfma_f32_16x16x32_bf16(wfrag, xb[kt], acc, 0, 0, 0);
        }
        if (node < N) {
            u32 lo = (u32)f2bf(acc[0]) | ((u32)f2bf(acc[1]) << 16);
            u32 hi = (u32)f2bf(acc[2]) | ((u32)f2bf(acc[3]) << 16);
            *(uint2*)(yp + ct * 16) = make_uint2(lo, hi);
        }
    }
}

__global__ void deg_kernel(const int* __restrict__ dst, int* __restrict__ deg, int E) {
    int e = blockIdx.x * blockDim.x + threadIdx.x;
    if (e < E) atomicAdd(&deg[dst[e]], 1);
}

// Block scan: per-block sums (Hillis-Steele, 256 threads)
__global__ void scan1_kernel(const int* __restrict__ deg, int* __restrict__ bsum, int N) {
    __shared__ int tmp[256];
    int tid = threadIdx.x;
    int i = blockIdx.x * 256 + tid;
    int v = (i < N) ? deg[i] : 0;
    tmp[tid] = v;
    __syncthreads();
    for (int off = 1; off < 256; off <<= 1) {
        int t = (tid >= off) ? tmp[tid - off] : 0;
        __syncthreads();
        tmp[tid] += t;
        __syncthreads();
    }
    if (tid == 255) bsum[blockIdx.x] = tmp[255];
}

// scan3: each block re-scans bsum (nb<=256) in LDS for its offset, then
// finishes rowptr/cursor/dis. (scan2 merged in.)
__global__ void scan3_kernel(const int* __restrict__ deg, const int* __restrict__ bsum,
                             int* __restrict__ rowptr, int* __restrict__ cursor,
                             float* __restrict__ dis, int N, int nb) {
    __shared__ int tmp[256];
    __shared__ int bs[256];
    int tid = threadIdx.x;
    int bv = (tid < nb) ? bsum[tid] : 0;
    bs[tid] = bv;
    __syncthreads();
    for (int off = 1; off < 256; off <<= 1) {
        int t = (tid >= off) ? bs[tid - off] : 0;
        __syncthreads();
        bs[tid] += t;
        __syncthreads();
    }
    int boff = bs[blockIdx.x] - ((blockIdx.x < nb) ? bsum[blockIdx.x] : 0);
    int i = blockIdx.x * 256 + tid;
    int v = (i < N) ? deg[i] : 0;
    tmp[tid] = v;
    __syncthreads();
    for (int off = 1; off < 256; off <<= 1) {
        int t = (tid >= off) ? tmp[tid - off] : 0;
        __syncthreads();
        tmp[tid] += t;
        __syncthreads();
    }
    int excl = tmp[tid] - v + boff;
    if (i < N) {
        rowptr[i] = excl;
        cursor[i] = excl;
        dis[i] = rsqrtf((float)(v < 1 ? 1 : v));
        if (i == N - 1) rowptr[N] = excl + v;
    }
}

__global__ void fill_kernel(const int* __restrict__ src, const int* __restrict__ dst,
                            const float* __restrict__ ew, const float* __restrict__ dis,
                            int* __restrict__ cursor, int2* __restrict__ csr, int E) {
    int e = blockIdx.x * blockDim.x + threadIdx.x;
    if (e >= E) return;
    int s = src[e], d = dst[e];
    float nm = dis[s] * ew[e] * dis[d];
    int pos = atomicAdd(&cursor[d], 1);
    csr[pos] = make_int2(s, __float_as_int(nm));
}

// One wave per destination node, gathering yh rows (512B, both batches bf16).
// Lane l: batch=l>>5, cols=(l&31)*4 (one uint2 = 4 bf16). CSR preloaded
// 64-wide + shuffle-broadcast; gathers in groups of 8 for MLP.
// Epilogue adds bias and writes final fp32 out[2][N][128].
__global__ __launch_bounds__(256) void agg_kernel(const uint2* __restrict__ yh,
                                                  const int* __restrict__ rowptr,
                                                  const int2* __restrict__ csr,
                                                  const float* __restrict__ bias,
                                                  float* __restrict__ out, int N) {
    int node = blockIdx.x * 4 + (threadIdx.x >> 6);
    if (node >= N) return;
    int lane = threadIdx.x & 63;
    int col = (lane & 31) * 4;
    float4 bv = *(const float4*)(bias + col);
    const uint2* xb = yh + lane;
    int beg = rowptr[node], end = rowptr[node + 1];
    float4 acc = make_float4(0.f, 0.f, 0.f, 0.f);
    for (int base = beg; base < end; base += 64) {
        int cnt = end - base;
        if (cnt > 64) cnt = 64;
        int2 p = make_int2(0, 0);
        if (lane < cnt) p = csr[base + lane];
        for (int j0 = 0; j0 < cnt; j0 += 8) {
            int m = cnt - j0;             // wave-uniform
            if (m > 8) m = 8;
            uint2 q[8];
            float nm[8];
#pragma unroll
            for (int j = 0; j < 8; ++j) {
                if (j < m) {
                    int s = __shfl(p.x, j0 + j);
                    nm[j] = __int_as_float(__shfl(p.y, j0 + j));
                    q[j] = xb[(size_t)s * 64];
                }
            }
#pragma unroll
            for (int j = 0; j < 8; ++j) {
                if (j < m) {
                    acc.x = fmaf(__uint_as_float(q[j].x << 16), nm[j], acc.x);
                    acc.y = fmaf(__uint_as_float(q[j].x & 0xffff0000u), nm[j], acc.y);
                    acc.z = fmaf(__uint_as_float(q[j].y << 16), nm[j], acc.z);
                    acc.w = fmaf(__uint_as_float(q[j].y & 0xffff0000u), nm[j], acc.w);
                }
            }
        }
    }
    int half = lane >> 5;
    acc.x += bv.x; acc.y += bv.y; acc.z += bv.z; acc.w += bv.w;
    *(float4*)(out + (size_t)half * N * 128 + (size_t)node * 128 + col) = acc;
}

extern "C" void kernel_launch(void* const* d_in, const int* in_sizes, int n_in,
                              void* d_out, int out_size, void* d_ws, size_t ws_size,
                              hipStream_t stream) {
    const float* x    = (const float*)d_in[0];
    const int*   eidx = (const int*)d_in[1];   // [2][E] flat: src then dst
    const float* ew   = (const float*)d_in[2];
    const float* W    = (const float*)d_in[3];
    const float* bias = (const float*)d_in[4];
    float* out = (float*)d_out;

    const int E = in_sizes[2];                 // edge_weight count
    const int N = in_sizes[0] / 256;           // B=2, F=128 -> N = size/(2*128)
    const int nb = (N + 255) / 256;            // scan blocks (must be <= 256)

    const int* src = eidx;
    const int* dst = eidx + E;

    // ws footprint ~32.1 MB — round-3-proven envelope. DO NOT GROW (round-6 overflow).
    char* w = (char*)d_ws;
    int*   deg    = (int*)w;   w += WS_ALIGN((size_t)N * 4);
    int*   rowptr = (int*)w;   w += WS_ALIGN((size_t)(N + 1) * 4);
    int*   cursor = (int*)w;   w += WS_ALIGN((size_t)N * 4);
    float* dis    = (float*)w; w += WS_ALIGN((size_t)N * 4);
    int*   bsum   = (int*)w;   w += WS_ALIGN((size_t)nb * 4);
    int2*  csr    = (int2*)w;  w += WS_ALIGN((size_t)E * 8);
    u16*   yh     = (u16*)w;   w += WS_ALIGN((size_t)N * 512);      // [N][2][128] bf16
    uint2* Wh     = (uint2*)w; w += WS_ALIGN((size_t)128 * 128 * 2);

    int pgrid = (N > 4096 ? N : 4096);
    hipLaunchKernelGGL(prep_kernel, dim3((pgrid + 255) / 256), dim3(256), 0, stream,
                       W, Wh, deg, N);
    int waves = (N + 15) / 16;
    hipLaunchKernelGGL(gemm_yh_kernel, dim3((waves + 3) / 4, 2), dim3(256), 0, stream,
                       x, (const u16*)Wh, yh, N);
    hipLaunchKernelGGL(deg_kernel,  dim3((E + 255) / 256), dim3(256), 0, stream, dst, deg, E);
    hipLaunchKernelGGL(scan1_kernel, dim3(nb), dim3(256), 0, stream, deg, bsum, N);
    hipLaunchKernelGGL(scan3_kernel, dim3(nb), dim3(256), 0, stream, deg, bsum, rowptr, cursor, dis, N, nb);
    hipLaunchKernelGGL(fill_kernel, dim3((E + 255) / 256), dim3(256), 0, stream,
                       src, dst, ew, dis, cursor, csr, E);
    hipLaunchKernelGGL(agg_kernel,  dim3((N + 3) / 4), dim3(256), 0, stream,
                       (const uint2*)yh, rowptr, csr, bias, out, N);
}

// Round 12
// 188.854 us; speedup vs baseline: 1.5576x; 1.0445x over previous
//
#include <hip/hip_runtime.h>
#include <hip/hip_fp16.h>

typedef unsigned int u32;
typedef unsigned short u16;
typedef __attribute__((ext_vector_type(8))) short bf16x8;
typedef __attribute__((ext_vector_type(4))) float f32x4;

#define WS_ALIGN(x) (((x) + 255) & ~(size_t)255)

__device__ inline u16 f2bf(float f) {
    u32 u = __float_as_uint(f);
    u32 r = (u + 0x7fffu + ((u >> 16) & 1u)) >> 16;   // RNE
    return (u16)r;
}

// Fused: zero deg[N]  +  W f32 -> Wh bf16 (4096 uint2 chunks)
__global__ void prep_kernel(const float* __restrict__ W, uint2* __restrict__ Wh,
                            int* __restrict__ deg, int N) {
    int t = blockIdx.x * 256 + threadIdx.x;
    if (t < N) deg[t] = 0;
    if (t < 4096) {
        float4 v = ((const float4*)W)[t];
        Wh[t] = make_uint2((u32)f2bf(v.x) | ((u32)f2bf(v.y) << 16),
                           (u32)f2bf(v.z) | ((u32)f2bf(v.w) << 16));
    }
}

// Y = X @ W^T computed BEFORE aggregation (linearity: Â(X)W^T = Â(XW^T)).
// One wave = 16 nodes of batch b (blockIdx.y). Swapped operands:
// A = W rows (D row = feature), B = x rows (D col = node) -> reg-packed stores.
// Identical A/B k-maps cancel the HW k-permutation (validated r7/r9/r10).
// D (verified m89): col = lane&15 (node), row = g*4+reg (feature-in-chunk)
__global__ __launch_bounds__(256) void gemm_yh_kernel(const float* __restrict__ x,
                                                      const u16* __restrict__ Wh,
                                                      u16* __restrict__ yh, int N) {
    int wv = blockIdx.x * 4 + (threadIdx.x >> 6);
    int r0 = wv * 16;
    if (r0 >= N) return;
    int b = blockIdx.y;
    int lane = threadIdx.x & 63;
    int l15 = lane & 15, g = lane >> 4;

    int xrow = r0 + l15;
    if (xrow >= N) xrow = N - 1;              // safe clamp (store is guarded)
    const float* xp = x + ((size_t)b * N + xrow) * 128 + g * 8;
    bf16x8 xb[4];
#pragma unroll
    for (int kt = 0; kt < 4; ++kt) {
        float4 u0 = *(const float4*)(xp + kt * 32);
        float4 u1 = *(const float4*)(xp + kt * 32 + 4);
        bf16x8 t;
        t[0] = (short)f2bf(u0.x); t[1] = (short)f2bf(u0.y);
        t[2] = (short)f2bf(u0.z); t[3] = (short)f2bf(u0.w);
        t[4] = (short)f2bf(u1.x); t[5] = (short)f2bf(u1.y);
        t[6] = (short)f2bf(u1.z); t[7] = (short)f2bf(u1.w);
        xb[kt] = t;
    }

    int node = r0 + l15;
    u16* yp = yh + (size_t)node * 256 + b * 128 + g * 4;
#pragma unroll
    for (int ct = 0; ct < 8; ++ct) {
        const u16* wp = Wh + (size_t)(ct * 16 + l15) * 128 + g * 8;
        f32x4 acc = {0.f, 0.f, 0.f, 0.f};
#pragma unroll
        for (int kt = 0; kt < 4; ++kt) {
            bf16x8 wfrag = *(const bf16x8*)(wp + kt * 32);
            acc = __builtin_amdgcn_mfma_f32_16x16x32_bf16(wfrag, xb[kt], acc, 0, 0, 0);
        }
        if (node < N) {
            u32 lo = (u32)f2bf(acc[0]) | ((u32)f2bf(acc[1]) << 16);
            u32 hi = (u32)f2bf(acc[2]) | ((u32)f2bf(acc[3]) << 16);
            *(uint2*)(yp + ct * 16) = make_uint2(lo, hi);
        }
    }
}

__global__ void deg_kernel(const int* __restrict__ dst, int* __restrict__ deg, int E) {
    int e = blockIdx.x * blockDim.x + threadIdx.x;
    if (e < E) atomicAdd(&deg[dst[e]], 1);
}

// Block scan: per-block sums (Hillis-Steele, 256 threads)
__global__ void scan1_kernel(const int* __restrict__ deg, int* __restrict__ bsum, int N) {
    __shared__ int tmp[256];
    int tid = threadIdx.x;
    int i = blockIdx.x * 256 + tid;
    int v = (i < N) ? deg[i] : 0;
    tmp[tid] = v;
    __syncthreads();
    for (int off = 1; off < 256; off <<= 1) {
        int t = (tid >= off) ? tmp[tid - off] : 0;
        __syncthreads();
        tmp[tid] += t;
        __syncthreads();
    }
    if (tid == 255) bsum[blockIdx.x] = tmp[255];
}

// scan3: each block re-scans bsum (nb<=256) in LDS for its offset, then
// finishes rowptr/cursor/dis. (scan2 merged in.)
__global__ void scan3_kernel(const int* __restrict__ deg, const int* __restrict__ bsum,
                             int* __restrict__ rowptr, int* __restrict__ cursor,
                             float* __restrict__ dis, int N, int nb) {
    __shared__ int tmp[256];
    __shared__ int bs[256];
    int tid = threadIdx.x;
    int bv = (tid < nb) ? bsum[tid] : 0;
    bs[tid] = bv;
    __syncthreads();
    for (int off = 1; off < 256; off <<= 1) {
        int t = (tid >= off) ? bs[tid - off] : 0;
        __syncthreads();
        bs[tid] += t;
        __syncthreads();
    }
    int boff = bs[blockIdx.x] - ((blockIdx.x < nb) ? bsum[blockIdx.x] : 0);
    int i = blockIdx.x * 256 + tid;
    int v = (i < N) ? deg[i] : 0;
    tmp[tid] = v;
    __syncthreads();
    for (int off = 1; off < 256; off <<= 1) {
        int t = (tid >= off) ? tmp[tid - off] : 0;
        __syncthreads();
        tmp[tid] += t;
        __syncthreads();
    }
    int excl = tmp[tid] - v + boff;
    if (i < N) {
        rowptr[i] = excl;
        cursor[i] = excl;
        dis[i] = rsqrtf((float)(v < 1 ? 1 : v));
        if (i == N - 1) rowptr[N] = excl + v;
    }
}

// csr entry: 4B packed = (fp16(norm) << 16) | src  (src < 65536 required; N=50000)
__global__ void fill_kernel(const int* __restrict__ src, const int* __restrict__ dst,
                            const float* __restrict__ ew, const float* __restrict__ dis,
                            int* __restrict__ cursor, u32* __restrict__ csr, int E) {
    int e = blockIdx.x * blockDim.x + threadIdx.x;
    if (e >= E) return;
    int s = src[e], d = dst[e];
    float nm = dis[s] * ew[e] * dis[d];
    int pos = atomicAdd(&cursor[d], 1);
    u32 h = (u32)__half_as_ushort(__float2half_rn(nm));
    csr[pos] = (h << 16) | (u32)s;
}

// One WAVE per destination node (64-thread blocks, node = blockIdx.x so all
// CSR indexing is provably uniform -> scalar-pipe s_loads, no shuffles).
// Lane l: batch=l>>5, cols=(l&31)*4; gathers one uint2 (4 bf16) per edge;
// wave gather = contiguous 512B yh row. Unrolled groups of 8 for MLP.
// Epilogue adds bias, writes fp32 out[2][N][128].
__global__ __launch_bounds__(64) void agg_kernel(const uint2* __restrict__ yh,
                                                 const int* __restrict__ rowptr,
                                                 const u32* __restrict__ csr,
                                                 const float* __restrict__ bias,
                                                 float* __restrict__ out, int N) {
    int node = blockIdx.x;
    int lane = threadIdx.x & 63;
    int col = (lane & 31) * 4;
    int half = lane >> 5;
    const uint2* xb = yh + lane;
    int beg = rowptr[node], end = rowptr[node + 1];
    float4 acc = make_float4(0.f, 0.f, 0.f, 0.f);

    int j0 = beg;
    for (; j0 + 8 <= end; j0 += 8) {
        u32 pv[8];
#pragma unroll
        for (int j = 0; j < 8; ++j) pv[j] = csr[j0 + j];      // uniform -> s_load
        uint2 q[8];
#pragma unroll
        for (int j = 0; j < 8; ++j) q[j] = xb[(size_t)(pv[j] & 0xffffu) * 64];
#pragma unroll
        for (int j = 0; j < 8; ++j) {
            float nm = __half2float(__ushort_as_half((u16)(pv[j] >> 16)));
            acc.x = fmaf(__uint_as_float(q[j].x << 16), nm, acc.x);
            acc.y = fmaf(__uint_as_float(q[j].x & 0xffff0000u), nm, acc.y);
            acc.z = fmaf(__uint_as_float(q[j].y << 16), nm, acc.z);
            acc.w = fmaf(__uint_as_float(q[j].y & 0xffff0000u), nm, acc.w);
        }
    }
    for (; j0 < end; ++j0) {
        u32 pv = csr[j0];
        float nm = __half2float(__ushort_as_half((u16)(pv >> 16)));
        uint2 v = xb[(size_t)(pv & 0xffffu) * 64];
        acc.x = fmaf(__uint_as_float(v.x << 16), nm, acc.x);
        acc.y = fmaf(__uint_as_float(v.x & 0xffff0000u), nm, acc.y);
        acc.z = fmaf(__uint_as_float(v.y << 16), nm, acc.z);
        acc.w = fmaf(__uint_as_float(v.y & 0xffff0000u), nm, acc.w);
    }

    float4 bv = *(const float4*)(bias + col);
    acc.x += bv.x; acc.y += bv.y; acc.z += bv.z; acc.w += bv.w;
    *(float4*)(out + (size_t)half * N * 128 + (size_t)node * 128 + col) = acc;
}

extern "C" void kernel_launch(void* const* d_in, const int* in_sizes, int n_in,
                              void* d_out, int out_size, void* d_ws, size_t ws_size,
                              hipStream_t stream) {
    const float* x    = (const float*)d_in[0];
    const int*   eidx = (const int*)d_in[1];   // [2][E] flat: src then dst
    const float* ew   = (const float*)d_in[2];
    const float* W    = (const float*)d_in[3];
    const float* bias = (const float*)d_in[4];
    float* out = (float*)d_out;

    const int E = in_sizes[2];                 // edge_weight count
    const int N = in_sizes[0] / 256;           // B=2, F=128 -> N = size/(2*128)
    const int nb = (N + 255) / 256;            // scan blocks (must be <= 256)

    const int* src = eidx;
    const int* dst = eidx + E;

    // ws footprint ~29 MB — below round-3-proven envelope. DO NOT GROW (round-6 overflow).
    char* w = (char*)d_ws;
    int*   deg    = (int*)w;   w += WS_ALIGN((size_t)N * 4);
    int*   rowptr = (int*)w;   w += WS_ALIGN((size_t)(N + 1) * 4);
    int*   cursor = (int*)w;   w += WS_ALIGN((size_t)N * 4);
    float* dis    = (float*)w; w += WS_ALIGN((size_t)N * 4);
    int*   bsum   = (int*)w;   w += WS_ALIGN((size_t)nb * 4);
    u32*   csr    = (u32*)w;   w += WS_ALIGN((size_t)E * 4);        // packed 4B/edge
    u16*   yh     = (u16*)w;   w += WS_ALIGN((size_t)N * 512);      // [N][2][128] bf16
    uint2* Wh     = (uint2*)w; w += WS_ALIGN((size_t)128 * 128 * 2);

    int pgrid = (N > 4096 ? N : 4096);
    hipLaunchKernelGGL(prep_kernel, dim3((pgrid + 255) / 256), dim3(256), 0, stream,
                       W, Wh, deg, N);
    int waves = (N + 15) / 16;
    hipLaunchKernelGGL(gemm_yh_kernel, dim3((waves + 3) / 4, 2), dim3(256), 0, stream,
                       x, (const u16*)Wh, yh, N);
    hipLaunchKernelGGL(deg_kernel,  dim3((E + 255) / 256), dim3(256), 0, stream, dst, deg, E);
    hipLaunchKernelGGL(scan1_kernel, dim3(nb), dim3(256), 0, stream, deg, bsum, N);
    hipLaunchKernelGGL(scan3_kernel, dim3(nb), dim3(256), 0, stream, deg, bsum, rowptr, cursor, dis, N, nb);
    hipLaunchKernelGGL(fill_kernel, dim3((E + 255) / 256), dim3(256), 0, stream,
                       src, dst, ew, dis, cursor, csr, E);
    hipLaunchKernelGGL(agg_kernel,  dim3(N), dim3(64), 0, stream,
                       (const uint2*)yh, rowptr, csr, bias, out, N);
}

// Round 13
// 176.178 us; speedup vs baseline: 1.6697x; 1.0719x over previous
//
#include <hip/hip_runtime.h>
#include <hip/hip_fp16.h>

typedef unsigned int u32;
typedef unsigned short u16;
typedef __attribute__((ext_vector_type(8))) short bf16x8;
typedef __attribute__((ext_vector_type(4))) float f32x4;

#define WS_ALIGN(x) (((x) + 255) & ~(size_t)255)

__device__ inline u16 f2bf(float f) {
    u32 u = __float_as_uint(f);
    u32 r = (u + 0x7fffu + ((u >> 16) & 1u)) >> 16;   // RNE
    return (u16)r;
}

// Fused: zero deg[N]  +  W f32 -> Wh bf16 (4096 uint2 chunks)
__global__ void prep_kernel(const float* __restrict__ W, uint2* __restrict__ Wh,
                            int* __restrict__ deg, int N) {
    int t = blockIdx.x * 256 + threadIdx.x;
    if (t < N) deg[t] = 0;
    if (t < 4096) {
        float4 v = ((const float4*)W)[t];
        Wh[t] = make_uint2((u32)f2bf(v.x) | ((u32)f2bf(v.y) << 16),
                           (u32)f2bf(v.z) | ((u32)f2bf(v.w) << 16));
    }
}

// Fused gemm + deg (block-role split; data-independent so deg hides under gemm).
// gemm role (blocks [0, 2*gpb)): Y = X@W^T, one wave = 16 nodes of one batch.
//   Swapped operands: A=W rows (D row=feature), B=x rows (D col=node).
//   Identical A/B k-maps cancel the HW k-permutation (validated r7/r9/r10).
//   D (verified m89): col = lane&15 (node), row = g*4+reg.
// deg role (blocks >= 2*gpb): 4 edges/thread via int4, atomicAdd histogram.
__global__ __launch_bounds__(256) void front_kernel(const float* __restrict__ x,
                                                    const u16* __restrict__ Wh,
                                                    const int* __restrict__ dst,
                                                    int* __restrict__ deg,
                                                    u16* __restrict__ yh,
                                                    int N, int E, int gpb) {
    int bid = blockIdx.x;
    if (bid < 2 * gpb) {
        int b = (bid >= gpb) ? 1 : 0;
        int gb = bid - b * gpb;
        int wv = gb * 4 + (threadIdx.x >> 6);
        int r0 = wv * 16;
        if (r0 >= N) return;
        int lane = threadIdx.x & 63;
        int l15 = lane & 15, g = lane >> 4;

        int xrow = r0 + l15;
        if (xrow >= N) xrow = N - 1;          // safe clamp (store is guarded)
        const float* xp = x + ((size_t)b * N + xrow) * 128 + g * 8;
        bf16x8 xb[4];
#pragma unroll
        for (int kt = 0; kt < 4; ++kt) {
            float4 u0 = *(const float4*)(xp + kt * 32);
            float4 u1 = *(const float4*)(xp + kt * 32 + 4);
            bf16x8 t;
            t[0] = (short)f2bf(u0.x); t[1] = (short)f2bf(u0.y);
            t[2] = (short)f2bf(u0.z); t[3] = (short)f2bf(u0.w);
            t[4] = (short)f2bf(u1.x); t[5] = (short)f2bf(u1.y);
            t[6] = (short)f2bf(u1.z); t[7] = (short)f2bf(u1.w);
            xb[kt] = t;
        }

        int node = r0 + l15;
        u16* yp = yh + (size_t)node * 256 + b * 128 + g * 4;
#pragma unroll
        for (int ct = 0; ct < 8; ++ct) {
            const u16* wp = Wh + (size_t)(ct * 16 + l15) * 128 + g * 8;
            f32x4 acc = {0.f, 0.f, 0.f, 0.f};
#pragma unroll
            for (int kt = 0; kt < 4; ++kt) {
                bf16x8 wfrag = *(const bf16x8*)(wp + kt * 32);
                acc = __builtin_amdgcn_mfma_f32_16x16x32_bf16(wfrag, xb[kt], acc, 0, 0, 0);
            }
            if (node < N) {
                u32 lo = (u32)f2bf(acc[0]) | ((u32)f2bf(acc[1]) << 16);
                u32 hi = (u32)f2bf(acc[2]) | ((u32)f2bf(acc[3]) << 16);
                *(uint2*)(yp + ct * 16) = make_uint2(lo, hi);
            }
        }
    } else {
        int e0 = ((bid - 2 * gpb) * 256 + threadIdx.x) * 4;
        if (e0 + 3 < E) {
            int4 d4 = *(const int4*)(dst + e0);
            atomicAdd(&deg[d4.x], 1);
            atomicAdd(&deg[d4.y], 1);
            atomicAdd(&deg[d4.z], 1);
            atomicAdd(&deg[d4.w], 1);
        } else {
            for (int e = e0; e < E; ++e) atomicAdd(&deg[dst[e]], 1);
        }
    }
}

// Block scan: per-block sums (Hillis-Steele, 256 threads)
__global__ void scan1_kernel(const int* __restrict__ deg, int* __restrict__ bsum, int N) {
    __shared__ int tmp[256];
    int tid = threadIdx.x;
    int i = blockIdx.x * 256 + tid;
    int v = (i < N) ? deg[i] : 0;
    tmp[tid] = v;
    __syncthreads();
    for (int off = 1; off < 256; off <<= 1) {
        int t = (tid >= off) ? tmp[tid - off] : 0;
        __syncthreads();
        tmp[tid] += t;
        __syncthreads();
    }
    if (tid == 255) bsum[blockIdx.x] = tmp[255];
}

// scan3: each block re-scans bsum (nb<=256) in LDS for its offset, then
// finishes rowptr/cursor/dis. (scan2 merged in.)
__global__ void scan3_kernel(const int* __restrict__ deg, const int* __restrict__ bsum,
                             int* __restrict__ rowptr, int* __restrict__ cursor,
                             float* __restrict__ dis, int N, int nb) {
    __shared__ int tmp[256];
    __shared__ int bs[256];
    int tid = threadIdx.x;
    int bv = (tid < nb) ? bsum[tid] : 0;
    bs[tid] = bv;
    __syncthreads();
    for (int off = 1; off < 256; off <<= 1) {
        int t = (tid >= off) ? bs[tid - off] : 0;
        __syncthreads();
        bs[tid] += t;
        __syncthreads();
    }
    int boff = bs[blockIdx.x] - ((blockIdx.x < nb) ? bsum[blockIdx.x] : 0);
    int i = blockIdx.x * 256 + tid;
    int v = (i < N) ? deg[i] : 0;
    tmp[tid] = v;
    __syncthreads();
    for (int off = 1; off < 256; off <<= 1) {
        int t = (tid >= off) ? tmp[tid - off] : 0;
        __syncthreads();
        tmp[tid] += t;
        __syncthreads();
    }
    int excl = tmp[tid] - v + boff;
    if (i < N) {
        rowptr[i] = excl;
        cursor[i] = excl;
        dis[i] = rsqrtf((float)(v < 1 ? 1 : v));
        if (i == N - 1) rowptr[N] = excl + v;
    }
}

// csr entry: 4B packed = (fp16(norm) << 16) | src  (src < 65536 required; N=50000)
// 4 edges per thread (int4/float4 loads).
__global__ void fill_kernel(const int* __restrict__ src, const int* __restrict__ dst,
                            const float* __restrict__ ew, const float* __restrict__ dis,
                            int* __restrict__ cursor, u32* __restrict__ csr, int E) {
    int e0 = (blockIdx.x * blockDim.x + threadIdx.x) * 4;
    if (e0 + 3 < E) {
        int4 s4 = *(const int4*)(src + e0);
        int4 d4 = *(const int4*)(dst + e0);
        float4 w4 = *(const float4*)(ew + e0);
        {
            float nm = dis[s4.x] * w4.x * dis[d4.x];
            int pos = atomicAdd(&cursor[d4.x], 1);
            csr[pos] = ((u32)__half_as_ushort(__float2half_rn(nm)) << 16) | (u32)s4.x;
        }
        {
            float nm = dis[s4.y] * w4.y * dis[d4.y];
            int pos = atomicAdd(&cursor[d4.y], 1);
            csr[pos] = ((u32)__half_as_ushort(__float2half_rn(nm)) << 16) | (u32)s4.y;
        }
        {
            float nm = dis[s4.z] * w4.z * dis[d4.z];
            int pos = atomicAdd(&cursor[d4.z], 1);
            csr[pos] = ((u32)__half_as_ushort(__float2half_rn(nm)) << 16) | (u32)s4.z;
        }
        {
            float nm = dis[s4.w] * w4.w * dis[d4.w];
            int pos = atomicAdd(&cursor[d4.w], 1);
            csr[pos] = ((u32)__half_as_ushort(__float2half_rn(nm)) << 16) | (u32)s4.w;
        }
    } else {
        for (int e = e0; e < E; ++e) {
            int s = src[e], d = dst[e];
            float nm = dis[s] * ew[e] * dis[d];
            int pos = atomicAdd(&cursor[d], 1);
            csr[pos] = ((u32)__half_as_ushort(__float2half_rn(nm)) << 16) | (u32)s;
        }
    }
}

// One WAVE per destination node (64-thread blocks, node = blockIdx.x so all
// CSR indexing is provably uniform -> scalar-pipe s_loads, no shuffles).
// Lane l: batch=l>>5, cols=(l&31)*4; gathers one uint2 (4 bf16) per edge;
// wave gather = contiguous 512B yh row. Unrolled groups of 8 for MLP.
// Epilogue adds bias, writes fp32 out[2][N][128].
__global__ __launch_bounds__(64) void agg_kernel(const uint2* __restrict__ yh,
                                                 const int* __restrict__ rowptr,
                                                 const u32* __restrict__ csr,
                                                 const float* __restrict__ bias,
                                                 float* __restrict__ out, int N) {
    int node = blockIdx.x;
    int lane = threadIdx.x & 63;
    int col = (lane & 31) * 4;
    int half = lane >> 5;
    const uint2* xb = yh + lane;
    int beg = rowptr[node], end = rowptr[node + 1];
    float4 acc = make_float4(0.f, 0.f, 0.f, 0.f);

    int j0 = beg;
    for (; j0 + 8 <= end; j0 += 8) {
        u32 pv[8];
#pragma unroll
        for (int j = 0; j < 8; ++j) pv[j] = csr[j0 + j];      // uniform -> s_load
        uint2 q[8];
#pragma unroll
        for (int j = 0; j < 8; ++j) q[j] = xb[(size_t)(pv[j] & 0xffffu) * 64];
#pragma unroll
        for (int j = 0; j < 8; ++j) {
            float nm = __half2float(__ushort_as_half((u16)(pv[j] >> 16)));
            acc.x = fmaf(__uint_as_float(q[j].x << 16), nm, acc.x);
            acc.y = fmaf(__uint_as_float(q[j].x & 0xffff0000u), nm, acc.y);
            acc.z = fmaf(__uint_as_float(q[j].y << 16), nm, acc.z);
            acc.w = fmaf(__uint_as_float(q[j].y & 0xffff0000u), nm, acc.w);
        }
    }
    for (; j0 < end; ++j0) {
        u32 pv = csr[j0];
        float nm = __half2float(__ushort_as_half((u16)(pv >> 16)));
        uint2 v = xb[(size_t)(pv & 0xffffu) * 64];
        acc.x = fmaf(__uint_as_float(v.x << 16), nm, acc.x);
        acc.y = fmaf(__uint_as_float(v.x & 0xffff0000u), nm, acc.y);
        acc.z = fmaf(__uint_as_float(v.y << 16), nm, acc.z);
        acc.w = fmaf(__uint_as_float(v.y & 0xffff0000u), nm, acc.w);
    }

    float4 bv = *(const float4*)(bias + col);
    acc.x += bv.x; acc.y += bv.y; acc.z += bv.z; acc.w += bv.w;
    *(float4*)(out + (size_t)half * N * 128 + (size_t)node * 128 + col) = acc;
}

extern "C" void kernel_launch(void* const* d_in, const int* in_sizes, int n_in,
                              void* d_out, int out_size, void* d_ws, size_t ws_size,
                              hipStream_t stream) {
    const float* x    = (const float*)d_in[0];
    const int*   eidx = (const int*)d_in[1];   // [2][E] flat: src then dst
    const float* ew   = (const float*)d_in[2];
    const float* W    = (const float*)d_in[3];
    const float* bias = (const float*)d_in[4];
    float* out = (float*)d_out;

    const int E = in_sizes[2];                 // edge_weight count
    const int N = in_sizes[0] / 256;           // B=2, F=128 -> N = size/(2*128)
    const int nb = (N + 255) / 256;            // scan blocks (must be <= 256)

    const int* src = eidx;
    const int* dst = eidx + E;

    // ws footprint ~29 MB — below round-3-proven envelope. DO NOT GROW (round-6 overflow).
    char* w = (char*)d_ws;
    int*   deg    = (int*)w;   w += WS_ALIGN((size_t)N * 4);
    int*   rowptr = (int*)w;   w += WS_ALIGN((size_t)(N + 1) * 4);
    int*   cursor = (int*)w;   w += WS_ALIGN((size_t)N * 4);
    float* dis    = (float*)w; w += WS_ALIGN((size_t)N * 4);
    int*   bsum   = (int*)w;   w += WS_ALIGN((size_t)nb * 4);
    u32*   csr    = (u32*)w;   w += WS_ALIGN((size_t)E * 4);        // packed 4B/edge
    u16*   yh     = (u16*)w;   w += WS_ALIGN((size_t)N * 512);      // [N][2][128] bf16
    uint2* Wh     = (uint2*)w; w += WS_ALIGN((size_t)128 * 128 * 2);

    int pgrid = (N > 4096 ? N : 4096);
    hipLaunchKernelGGL(prep_kernel, dim3((pgrid + 255) / 256), dim3(256), 0, stream,
                       W, Wh, deg, N);
    int gpb = ((N + 15) / 16 + 3) / 4;                    // gemm blocks per batch
    int degBlocks = ((E + 3) / 4 + 255) / 256;
    hipLaunchKernelGGL(front_kernel, dim3(2 * gpb + degBlocks), dim3(256), 0, stream,
                       x, (const u16*)Wh, dst, deg, yh, N, E, gpb);
    hipLaunchKernelGGL(scan1_kernel, dim3(nb), dim3(256), 0, stream, deg, bsum, N);
    hipLaunchKernelGGL(scan3_kernel, dim3(nb), dim3(256), 0, stream, deg, bsum, rowptr, cursor, dis, N, nb);
    hipLaunchKernelGGL(fill_kernel, dim3(((E + 3) / 4 + 255) / 256), dim3(256), 0, stream,
                       src, dst, ew, dis, cursor, csr, E);
    hipLaunchKernelGGL(agg_kernel,  dim3(N), dim3(64), 0, stream,
                       (const uint2*)yh, rowptr, csr, bias, out, N);
}

// Round 14
// 168.308 us; speedup vs baseline: 1.7477x; 1.0468x over previous
//
#include <hip/hip_runtime.h>
#include <hip/hip_fp16.h>

typedef unsigned int u32;
typedef unsigned short u16;
typedef __attribute__((ext_vector_type(8))) short bf16x8;
typedef __attribute__((ext_vector_type(4))) float f32x4;

#define WS_ALIGN(x) (((x) + 255) & ~(size_t)255)

__device__ inline u16 f2bf(float f) {
    u32 u = __float_as_uint(f);
    u32 r = (u + 0x7fffu + ((u >> 16) & 1u)) >> 16;   // RNE
    return (u16)r;
}

// Fused: zero deg[N]  +  W f32 -> Wh bf16 (4096 uint2 chunks)
__global__ void prep_kernel(const float* __restrict__ W, uint2* __restrict__ Wh,
                            int* __restrict__ deg, int N) {
    int t = blockIdx.x * 256 + threadIdx.x;
    if (t < N) deg[t] = 0;
    if (t < 4096) {
        float4 v = ((const float4*)W)[t];
        Wh[t] = make_uint2((u32)f2bf(v.x) | ((u32)f2bf(v.y) << 16),
                           (u32)f2bf(v.z) | ((u32)f2bf(v.w) << 16));
    }
}

// Fused gemm + deg (block-role split).
// gemm role: one wave = 32 nodes (2 m-tiles of 16) of one batch. xb[2][4]
// resident (32 VGPR); per ct the 4 Wh loads feed 8 MFMAs (2x ILP vs r13).
// Swapped operands: A=W rows, B=x rows; identical A/B k-maps cancel the HW
// k-permutation (validated r7/r9/r10). D (m89): col=lane&15 (node), row=g*4+reg.
// deg role: 4 edges/thread via int4, atomicAdd histogram.
__global__ __launch_bounds__(256) void front_kernel(const float* __restrict__ x,
                                                    const u16* __restrict__ Wh,
                                                    const int* __restrict__ dst,
                                                    int* __restrict__ deg,
                                                    u16* __restrict__ yh,
                                                    int N, int E, int gpb) {
    int bid = blockIdx.x;
    if (bid < 2 * gpb) {
        int b = (bid >= gpb) ? 1 : 0;
        int gb = bid - b * gpb;
        int wv = gb * 4 + (threadIdx.x >> 6);
        int r0 = wv * 32;
        if (r0 >= N) return;
        int lane = threadIdx.x & 63;
        int l15 = lane & 15, g = lane >> 4;

        bf16x8 xb[2][4];
#pragma unroll
        for (int m = 0; m < 2; ++m) {
            int xrow = r0 + m * 16 + l15;
            if (xrow >= N) xrow = N - 1;      // safe clamp (store is guarded)
            const float* xp = x + ((size_t)b * N + xrow) * 128 + g * 8;
#pragma unroll
            for (int kt = 0; kt < 4; ++kt) {
                float4 u0 = *(const float4*)(xp + kt * 32);
                float4 u1 = *(const float4*)(xp + kt * 32 + 4);
                bf16x8 t;
                t[0] = (short)f2bf(u0.x); t[1] = (short)f2bf(u0.y);
                t[2] = (short)f2bf(u0.z); t[3] = (short)f2bf(u0.w);
                t[4] = (short)f2bf(u1.x); t[5] = (short)f2bf(u1.y);
                t[6] = (short)f2bf(u1.z); t[7] = (short)f2bf(u1.w);
                xb[m][kt] = t;
            }
        }

        int n0 = r0 + l15, n1 = r0 + 16 + l15;
        u16* yp0 = yh + (size_t)n0 * 256 + b * 128 + g * 4;
        u16* yp1 = yh + (size_t)n1 * 256 + b * 128 + g * 4;
#pragma unroll
        for (int ct = 0; ct < 8; ++ct) {
            const u16* wp = Wh + (size_t)(ct * 16 + l15) * 128 + g * 8;
            f32x4 a0 = {0.f, 0.f, 0.f, 0.f};
            f32x4 a1 = {0.f, 0.f, 0.f, 0.f};
#pragma unroll
            for (int kt = 0; kt < 4; ++kt) {
                bf16x8 wf = *(const bf16x8*)(wp + kt * 32);
                a0 = __builtin_amdgcn_mfma_f32_16x16x32_bf16(wf, xb[0][kt], a0, 0, 0, 0);
                a1 = __builtin_amdgcn_mfma_f32_16x16x32_bf16(wf, xb[1][kt], a1, 0, 0, 0);
            }
            if (n0 < N) {
                u32 lo = (u32)f2bf(a0[0]) | ((u32)f2bf(a0[1]) << 16);
                u32 hi = (u32)f2bf(a0[2]) | ((u32)f2bf(a0[3]) << 16);
                *(uint2*)(yp0 + ct * 16) = make_uint2(lo, hi);
            }
            if (n1 < N) {
                u32 lo = (u32)f2bf(a1[0]) | ((u32)f2bf(a1[1]) << 16);
                u32 hi = (u32)f2bf(a1[2]) | ((u32)f2bf(a1[3]) << 16);
                *(uint2*)(yp1 + ct * 16) = make_uint2(lo, hi);
            }
        }
    } else {
        int e0 = ((bid - 2 * gpb) * 256 + threadIdx.x) * 4;
        if (e0 + 3 < E) {
            int4 d4 = *(const int4*)(dst + e0);
            atomicAdd(&deg[d4.x], 1);
            atomicAdd(&deg[d4.y], 1);
            atomicAdd(&deg[d4.z], 1);
            atomicAdd(&deg[d4.w], 1);
        } else {
            for (int e = e0; e < E; ++e) atomicAdd(&deg[dst[e]], 1);
        }
    }
}

// Block scan: per-block sums; 4 elems/thread (1024/block), Hillis-Steele.
__global__ void scan1_kernel(const int* __restrict__ deg, int* __restrict__ bsum, int N) {
    __shared__ int tmp[256];
    int tid = threadIdx.x;
    int i0 = blockIdx.x * 1024 + tid * 4;
    int s = 0;
    if (i0 + 3 < N) {
        int4 v = *(const int4*)(deg + i0);
        s = v.x + v.y + v.z + v.w;
    } else {
        for (int j = 0; j < 4; ++j) if (i0 + j < N) s += deg[i0 + j];
    }
    tmp[tid] = s;
    __syncthreads();
    for (int off = 1; off < 256; off <<= 1) {
        int t = (tid >= off) ? tmp[tid - off] : 0;
        __syncthreads();
        tmp[tid] += t;
        __syncthreads();
    }
    if (tid == 255) bsum[blockIdx.x] = tmp[255];
}

// scan3: re-scan bsum (nb<=256) in LDS for block offset, then 4-elem/thread
// local prefix to finish rowptr/cursor/dis.
__global__ void scan3_kernel(const int* __restrict__ deg, const int* __restrict__ bsum,
                             int* __restrict__ rowptr, int* __restrict__ cursor,
                             float* __restrict__ dis, int N, int nb) {
    __shared__ int tmp[256];
    __shared__ int bs[256];
    int tid = threadIdx.x;
    bs[tid] = (tid < nb) ? bsum[tid] : 0;
    __syncthreads();
    for (int off = 1; off < 256; off <<= 1) {
        int t = (tid >= off) ? bs[tid - off] : 0;
        __syncthreads();
        bs[tid] += t;
        __syncthreads();
    }
    int boff = bs[blockIdx.x] - bsum[blockIdx.x];

    int i0 = blockIdx.x * 1024 + tid * 4;
    int4 v;
    if (i0 + 3 < N) {
        v = *(const int4*)(deg + i0);
    } else {
        v.x = (i0 < N) ? deg[i0] : 0;
        v.y = (i0 + 1 < N) ? deg[i0 + 1] : 0;
        v.z = (i0 + 2 < N) ? deg[i0 + 2] : 0;
        v.w = (i0 + 3 < N) ? deg[i0 + 3] : 0;
    }
    int s = v.x + v.y + v.z + v.w;
    tmp[tid] = s;
    __syncthreads();
    for (int off = 1; off < 256; off <<= 1) {
        int t = (tid >= off) ? tmp[tid - off] : 0;
        __syncthreads();
        tmp[tid] += t;
        __syncthreads();
    }
    int e0 = tmp[tid] - s + boff;
    int e1 = e0 + v.x, e2 = e1 + v.y, e3 = e2 + v.z;
    if (i0 < N) {
        rowptr[i0] = e0; cursor[i0] = e0;
        dis[i0] = rsqrtf((float)(v.x < 1 ? 1 : v.x));
        if (i0 == N - 1) rowptr[N] = e1;
    }
    if (i0 + 1 < N) {
        rowptr[i0 + 1] = e1; cursor[i0 + 1] = e1;
        dis[i0 + 1] = rsqrtf((float)(v.y < 1 ? 1 : v.y));
        if (i0 + 1 == N - 1) rowptr[N] = e2;
    }
    if (i0 + 2 < N) {
        rowptr[i0 + 2] = e2; cursor[i0 + 2] = e2;
        dis[i0 + 2] = rsqrtf((float)(v.z < 1 ? 1 : v.z));
        if (i0 + 2 == N - 1) rowptr[N] = e3;
    }
    if (i0 + 3 < N) {
        rowptr[i0 + 3] = e3; cursor[i0 + 3] = e3;
        dis[i0 + 3] = rsqrtf((float)(v.w < 1 ? 1 : v.w));
        if (i0 + 3 == N - 1) rowptr[N] = e3 + v.w;
    }
}

// csr entry: 4B packed = (fp16(norm) << 16) | src  (src < 65536 required; N=50000)
// 4 edges per thread (int4/float4 loads).
__global__ void fill_kernel(const int* __restrict__ src, const int* __restrict__ dst,
                            const float* __restrict__ ew, const float* __restrict__ dis,
                            int* __restrict__ cursor, u32* __restrict__ csr, int E) {
    int e0 = (blockIdx.x * blockDim.x + threadIdx.x) * 4;
    if (e0 + 3 < E) {
        int4 s4 = *(const int4*)(src + e0);
        int4 d4 = *(const int4*)(dst + e0);
        float4 w4 = *(const float4*)(ew + e0);
        {
            float nm = dis[s4.x] * w4.x * dis[d4.x];
            int pos = atomicAdd(&cursor[d4.x], 1);
            csr[pos] = ((u32)__half_as_ushort(__float2half_rn(nm)) << 16) | (u32)s4.x;
        }
        {
            float nm = dis[s4.y] * w4.y * dis[d4.y];
            int pos = atomicAdd(&cursor[d4.y], 1);
            csr[pos] = ((u32)__half_as_ushort(__float2half_rn(nm)) << 16) | (u32)s4.y;
        }
        {
            float nm = dis[s4.z] * w4.z * dis[d4.z];
            int pos = atomicAdd(&cursor[d4.z], 1);
            csr[pos] = ((u32)__half_as_ushort(__float2half_rn(nm)) << 16) | (u32)s4.z;
        }
        {
            float nm = dis[s4.w] * w4.w * dis[d4.w];
            int pos = atomicAdd(&cursor[d4.w], 1);
            csr[pos] = ((u32)__half_as_ushort(__float2half_rn(nm)) << 16) | (u32)s4.w;
        }
    } else {
        for (int e = e0; e < E; ++e) {
            int s = src[e], d = dst[e];
            float nm = dis[s] * ew[e] * dis[d];
            int pos = atomicAdd(&cursor[d], 1);
            csr[pos] = ((u32)__half_as_ushort(__float2half_rn(nm)) << 16) | (u32)s;
        }
    }
}

// One WAVE per destination node (64-thread blocks, node = blockIdx.x so all
// CSR indexing is provably uniform -> scalar-pipe s_loads, no shuffles).
// Lane l: batch=l>>5, cols=(l&31)*4; gathers one uint2 (4 bf16) per edge;
// wave gather = contiguous 512B yh row. Unrolled groups of 8 for MLP.
// Epilogue adds bias, writes fp32 out[2][N][128].
__global__ __launch_bounds__(64) void agg_kernel(const uint2* __restrict__ yh,
                                                 const int* __restrict__ rowptr,
                                                 const u32* __restrict__ csr,
                                                 const float* __restrict__ bias,
                                                 float* __restrict__ out, int N) {
    int node = blockIdx.x;
    int lane = threadIdx.x & 63;
    int col = (lane & 31) * 4;
    int half = lane >> 5;
    const uint2* xb = yh + lane;
    int beg = rowptr[node], end = rowptr[node + 1];
    float4 acc = make_float4(0.f, 0.f, 0.f, 0.f);

    int j0 = beg;
    for (; j0 + 8 <= end; j0 += 8) {
        u32 pv[8];
#pragma unroll
        for (int j = 0; j < 8; ++j) pv[j] = csr[j0 + j];      // uniform -> s_load
        uint2 q[8];
#pragma unroll
        for (int j = 0; j < 8; ++j) q[j] = xb[(size_t)(pv[j] & 0xffffu) * 64];
#pragma unroll
        for (int j = 0; j < 8; ++j) {
            float nm = __half2float(__ushort_as_half((u16)(pv[j] >> 16)));
            acc.x = fmaf(__uint_as_float(q[j].x << 16), nm, acc.x);
            acc.y = fmaf(__uint_as_float(q[j].x & 0xffff0000u), nm, acc.y);
            acc.z = fmaf(__uint_as_float(q[j].y << 16), nm, acc.z);
            acc.w = fmaf(__uint_as_float(q[j].y & 0xffff0000u), nm, acc.w);
        }
    }
    for (; j0 < end; ++j0) {
        u32 pv = csr[j0];
        float nm = __half2float(__ushort_as_half((u16)(pv >> 16)));
        uint2 v = xb[(size_t)(pv & 0xffffu) * 64];
        acc.x = fmaf(__uint_as_float(v.x << 16), nm, acc.x);
        acc.y = fmaf(__uint_as_float(v.x & 0xffff0000u), nm, acc.y);
        acc.z = fmaf(__uint_as_float(v.y << 16), nm, acc.z);
        acc.w = fmaf(__uint_as_float(v.y & 0xffff0000u), nm, acc.w);
    }

    float4 bv = *(const float4*)(bias + col);
    acc.x += bv.x; acc.y += bv.y; acc.z += bv.z; acc.w += bv.w;
    *(float4*)(out + (size_t)half * N * 128 + (size_t)node * 128 + col) = acc;
}

extern "C" void kernel_launch(void* const* d_in, const int* in_sizes, int n_in,
                              void* d_out, int out_size, void* d_ws, size_t ws_size,
                              hipStream_t stream) {
    const float* x    = (const float*)d_in[0];
    const int*   eidx = (const int*)d_in[1];   // [2][E] flat: src then dst
    const float* ew   = (const float*)d_in[2];
    const float* W    = (const float*)d_in[3];
    const float* bias = (const float*)d_in[4];
    float* out = (float*)d_out;

    const int E = in_sizes[2];                 // edge_weight count
    const int N = in_sizes[0] / 256;           // B=2, F=128 -> N = size/(2*128)
    const int nb = (N + 1023) / 1024;          // scan blocks (must be <= 256)

    const int* src = eidx;
    const int* dst = eidx + E;

    // ws footprint ~29 MB — below round-3-proven envelope. DO NOT GROW (round-6 overflow).
    char* w = (char*)d_ws;
    int*   deg    = (int*)w;   w += WS_ALIGN((size_t)N * 4);
    int*   rowptr = (int*)w;   w += WS_ALIGN((size_t)(N + 1) * 4);
    int*   cursor = (int*)w;   w += WS_ALIGN((size_t)N * 4);
    float* dis    = (float*)w; w += WS_ALIGN((size_t)N * 4);
    int*   bsum   = (int*)w;   w += WS_ALIGN((size_t)nb * 4);
    u32*   csr    = (u32*)w;   w += WS_ALIGN((size_t)E * 4);        // packed 4B/edge
    u16*   yh     = (u16*)w;   w += WS_ALIGN((size_t)N * 512);      // [N][2][128] bf16
    uint2* Wh     = (uint2*)w; w += WS_ALIGN((size_t)128 * 128 * 2);

    int pgrid = (N > 4096 ? N : 4096);
    hipLaunchKernelGGL(prep_kernel, dim3((pgrid + 255) / 256), dim3(256), 0, stream,
                       W, Wh, deg, N);
    int gpb = ((N + 31) / 32 + 3) / 4;                    // gemm blocks per batch
    int degBlocks = ((E + 3) / 4 + 255) / 256;
    hipLaunchKernelGGL(front_kernel, dim3(2 * gpb + degBlocks), dim3(256), 0, stream,
                       x, (const u16*)Wh, dst, deg, yh, N, E, gpb);
    hipLaunchKernelGGL(scan1_kernel, dim3(nb), dim3(256), 0, stream, deg, bsum, N);
    hipLaunchKernelGGL(scan3_kernel, dim3(nb), dim3(256), 0, stream, deg, bsum, rowptr, cursor, dis, N, nb);
    hipLaunchKernelGGL(fill_kernel, dim3(((E + 3) / 4 + 255) / 256), dim3(256), 0, stream,
                       src, dst, ew, dis, cursor, csr, E);
    hipLaunchKernelGGL(agg_kernel,  dim3(N), dim3(64), 0, stream,
                       (const uint2*)yh, rowptr, csr, bias, out, N);
}

// Round 15
// 164.455 us; speedup vs baseline: 1.7887x; 1.0234x over previous
//
#include <hip/hip_runtime.h>
#include <hip/hip_fp16.h>

typedef unsigned int u32;
typedef unsigned short u16;
typedef __attribute__((ext_vector_type(8))) short bf16x8;
typedef __attribute__((ext_vector_type(4))) float f32x4;

#define WS_ALIGN(x) (((x) + 255) & ~(size_t)255)

__device__ inline u16 f2bf(float f) {
    u32 u = __float_as_uint(f);
    u32 r = (u + 0x7fffu + ((u >> 16) & 1u)) >> 16;   // RNE
    return (u16)r;
}

// Fused: zero deg[N]  +  W f32 -> Wh bf16 (4096 uint2 chunks)
__global__ void prep_kernel(const float* __restrict__ W, uint2* __restrict__ Wh,
                            int* __restrict__ deg, int N) {
    int t = blockIdx.x * 256 + threadIdx.x;
    if (t < N) deg[t] = 0;
    if (t < 4096) {
        float4 v = ((const float4*)W)[t];
        Wh[t] = make_uint2((u32)f2bf(v.x) | ((u32)f2bf(v.y) << 16),
                           (u32)f2bf(v.z) | ((u32)f2bf(v.w) << 16));
    }
}

// Fused gemm + deg (block-role split).
// gemm role: one wave = 32 nodes (2 m-tiles of 16) of one batch. xb[2][4]
// resident; per ct the 4 Wh loads feed 8 MFMAs. Swapped operands: A=W rows,
// B=x rows; identical A/B k-maps cancel the HW k-permutation (validated
// r7/r9/r10). D (m89): col=lane&15 (node), row=g*4+reg.
// deg role: 4 edges/thread via int4, atomicAdd histogram.
__global__ __launch_bounds__(256) void front_kernel(const float* __restrict__ x,
                                                    const u16* __restrict__ Wh,
                                                    const int* __restrict__ dst,
                                                    int* __restrict__ deg,
                                                    u16* __restrict__ yh,
                                                    int N, int E, int gpb) {
    int bid = blockIdx.x;
    if (bid < 2 * gpb) {
        int b = (bid >= gpb) ? 1 : 0;
        int gb = bid - b * gpb;
        int wv = gb * 4 + (threadIdx.x >> 6);
        int r0 = wv * 32;
        if (r0 >= N) return;
        int lane = threadIdx.x & 63;
        int l15 = lane & 15, g = lane >> 4;

        bf16x8 xb[2][4];
#pragma unroll
        for (int m = 0; m < 2; ++m) {
            int xrow = r0 + m * 16 + l15;
            if (xrow >= N) xrow = N - 1;      // safe clamp (store is guarded)
            const float* xp = x + ((size_t)b * N + xrow) * 128 + g * 8;
#pragma unroll
            for (int kt = 0; kt < 4; ++kt) {
                float4 u0 = *(const float4*)(xp + kt * 32);
                float4 u1 = *(const float4*)(xp + kt * 32 + 4);
                bf16x8 t;
                t[0] = (short)f2bf(u0.x); t[1] = (short)f2bf(u0.y);
                t[2] = (short)f2bf(u0.z); t[3] = (short)f2bf(u0.w);
                t[4] = (short)f2bf(u1.x); t[5] = (short)f2bf(u1.y);
                t[6] = (short)f2bf(u1.z); t[7] = (short)f2bf(u1.w);
                xb[m][kt] = t;
            }
        }

        int n0 = r0 + l15, n1 = r0 + 16 + l15;
        u16* yp0 = yh + (size_t)n0 * 256 + b * 128 + g * 4;
        u16* yp1 = yh + (size_t)n1 * 256 + b * 128 + g * 4;
#pragma unroll
        for (int ct = 0; ct < 8; ++ct) {
            const u16* wp = Wh + (size_t)(ct * 16 + l15) * 128 + g * 8;
            f32x4 a0 = {0.f, 0.f, 0.f, 0.f};
            f32x4 a1 = {0.f, 0.f, 0.f, 0.f};
#pragma unroll
            for (int kt = 0; kt < 4; ++kt) {
                bf16x8 wf = *(const bf16x8*)(wp + kt * 32);
                a0 = __builtin_amdgcn_mfma_f32_16x16x32_bf16(wf, xb[0][kt], a0, 0, 0, 0);
                a1 = __builtin_amdgcn_mfma_f32_16x16x32_bf16(wf, xb[1][kt], a1, 0, 0, 0);
            }
            if (n0 < N) {
                u32 lo = (u32)f2bf(a0[0]) | ((u32)f2bf(a0[1]) << 16);
                u32 hi = (u32)f2bf(a0[2]) | ((u32)f2bf(a0[3]) << 16);
                *(uint2*)(yp0 + ct * 16) = make_uint2(lo, hi);
            }
            if (n1 < N) {
                u32 lo = (u32)f2bf(a1[0]) | ((u32)f2bf(a1[1]) << 16);
                u32 hi = (u32)f2bf(a1[2]) | ((u32)f2bf(a1[3]) << 16);
                *(uint2*)(yp1 + ct * 16) = make_uint2(lo, hi);
            }
        }
    } else {
        int e0 = ((bid - 2 * gpb) * 256 + threadIdx.x) * 4;
        if (e0 + 3 < E) {
            int4 d4 = *(const int4*)(dst + e0);
            atomicAdd(&deg[d4.x], 1);
            atomicAdd(&deg[d4.y], 1);
            atomicAdd(&deg[d4.z], 1);
            atomicAdd(&deg[d4.w], 1);
        } else {
            for (int e = e0; e < E; ++e) atomicAdd(&deg[dst[e]], 1);
        }
    }
}

// Block scan: per-block sums; 4 elems/thread (1024/block), Hillis-Steele.
__global__ void scan1_kernel(const int* __restrict__ deg, int* __restrict__ bsum, int N) {
    __shared__ int tmp[256];
    int tid = threadIdx.x;
    int i0 = blockIdx.x * 1024 + tid * 4;
    int s = 0;
    if (i0 + 3 < N) {
        int4 v = *(const int4*)(deg + i0);
        s = v.x + v.y + v.z + v.w;
    } else {
        for (int j = 0; j < 4; ++j) if (i0 + j < N) s += deg[i0 + j];
    }
    tmp[tid] = s;
    __syncthreads();
    for (int off = 1; off < 256; off <<= 1) {
        int t = (tid >= off) ? tmp[tid - off] : 0;
        __syncthreads();
        tmp[tid] += t;
        __syncthreads();
    }
    if (tid == 255) bsum[blockIdx.x] = tmp[255];
}

// scan3: re-scan bsum (nb<=256) in LDS for block offset, then 4-elem/thread
// local prefix to finish rowptr/cursor/dis.
__global__ void scan3_kernel(const int* __restrict__ deg, const int* __restrict__ bsum,
                             int* __restrict__ rowptr, int* __restrict__ cursor,
                             float* __restrict__ dis, int N, int nb) {
    __shared__ int tmp[256];
    __shared__ int bs[256];
    int tid = threadIdx.x;
    bs[tid] = (tid < nb) ? bsum[tid] : 0;
    __syncthreads();
    for (int off = 1; off < 256; off <<= 1) {
        int t = (tid >= off) ? bs[tid - off] : 0;
        __syncthreads();
        bs[tid] += t;
        __syncthreads();
    }
    int boff = bs[blockIdx.x] - bsum[blockIdx.x];

    int i0 = blockIdx.x * 1024 + tid * 4;
    int4 v;
    if (i0 + 3 < N) {
        v = *(const int4*)(deg + i0);
    } else {
        v.x = (i0 < N) ? deg[i0] : 0;
        v.y = (i0 + 1 < N) ? deg[i0 + 1] : 0;
        v.z = (i0 + 2 < N) ? deg[i0 + 2] : 0;
        v.w = (i0 + 3 < N) ? deg[i0 + 3] : 0;
    }
    int s = v.x + v.y + v.z + v.w;
    tmp[tid] = s;
    __syncthreads();
    for (int off = 1; off < 256; off <<= 1) {
        int t = (tid >= off) ? tmp[tid - off] : 0;
        __syncthreads();
        tmp[tid] += t;
        __syncthreads();
    }
    int e0 = tmp[tid] - s + boff;
    int e1 = e0 + v.x, e2 = e1 + v.y, e3 = e2 + v.z;
    if (i0 < N) {
        rowptr[i0] = e0; cursor[i0] = e0;
        dis[i0] = rsqrtf((float)(v.x < 1 ? 1 : v.x));
        if (i0 == N - 1) rowptr[N] = e1;
    }
    if (i0 + 1 < N) {
        rowptr[i0 + 1] = e1; cursor[i0 + 1] = e1;
        dis[i0 + 1] = rsqrtf((float)(v.y < 1 ? 1 : v.y));
        if (i0 + 1 == N - 1) rowptr[N] = e2;
    }
    if (i0 + 2 < N) {
        rowptr[i0 + 2] = e2; cursor[i0 + 2] = e2;
        dis[i0 + 2] = rsqrtf((float)(v.z < 1 ? 1 : v.z));
        if (i0 + 2 == N - 1) rowptr[N] = e3;
    }
    if (i0 + 3 < N) {
        rowptr[i0 + 3] = e3; cursor[i0 + 3] = e3;
        dis[i0 + 3] = rsqrtf((float)(v.w < 1 ? 1 : v.w));
        if (i0 + 3 == N - 1) rowptr[N] = e3 + v.w;
    }
}

// csr entry: 4B packed = (fp16(norm) << 16) | src  (src < 65536 required; N=50000)
// 4 edges per thread (int4/float4 loads).
__global__ void fill_kernel(const int* __restrict__ src, const int* __restrict__ dst,
                            const float* __restrict__ ew, const float* __restrict__ dis,
                            int* __restrict__ cursor, u32* __restrict__ csr, int E) {
    int e0 = (blockIdx.x * blockDim.x + threadIdx.x) * 4;
    if (e0 + 3 < E) {
        int4 s4 = *(const int4*)(src + e0);
        int4 d4 = *(const int4*)(dst + e0);
        float4 w4 = *(const float4*)(ew + e0);
        {
            float nm = dis[s4.x] * w4.x * dis[d4.x];
            int pos = atomicAdd(&cursor[d4.x], 1);
            csr[pos] = ((u32)__half_as_ushort(__float2half_rn(nm)) << 16) | (u32)s4.x;
        }
        {
            float nm = dis[s4.y] * w4.y * dis[d4.y];
            int pos = atomicAdd(&cursor[d4.y], 1);
            csr[pos] = ((u32)__half_as_ushort(__float2half_rn(nm)) << 16) | (u32)s4.y;
        }
        {
            float nm = dis[s4.z] * w4.z * dis[d4.z];
            int pos = atomicAdd(&cursor[d4.z], 1);
            csr[pos] = ((u32)__half_as_ushort(__float2half_rn(nm)) << 16) | (u32)s4.z;
        }
        {
            float nm = dis[s4.w] * w4.w * dis[d4.w];
            int pos = atomicAdd(&cursor[d4.w], 1);
            csr[pos] = ((u32)__half_as_ushort(__float2half_rn(nm)) << 16) | (u32)s4.w;
        }
    } else {
        for (int e = e0; e < E; ++e) {
            int s = src[e], d = dst[e];
            float nm = dis[s] * ew[e] * dis[d];
            int pos = atomicAdd(&cursor[d], 1);
            csr[pos] = ((u32)__half_as_ushort(__float2half_rn(nm)) << 16) | (u32)s;
        }
    }
}

// One WAVE per (node, batch): grid (N, 2), 64-thread blocks. Linear dispatch
// order runs all batch-0 blocks first -> gather working set per phase is the
// 12.8MB batch half (vs 25.6MB) -> higher L2 hit rate. node = blockIdx.x so
// CSR indexing is provably uniform (scalar s_loads). Lane l owns 2 features:
// one dword (2 bf16) of the 256B row; wave gather = contiguous 256B.
// Unrolled groups of 8 for MLP. Epilogue adds bias, writes fp32 out.
__global__ __launch_bounds__(64) void agg_kernel(const u32* __restrict__ yh,
                                                 const int* __restrict__ rowptr,
                                                 const u32* __restrict__ csr,
                                                 const float* __restrict__ bias,
                                                 float* __restrict__ out, int N) {
    int node = blockIdx.x;
    int b = blockIdx.y;
    int lane = threadIdx.x;                 // 0..63
    const u32* xb = yh + (size_t)b * 64 + lane;   // row base: + node*128 (u32 units)
    int beg = rowptr[node], end = rowptr[node + 1];
    float2 acc = make_float2(0.f, 0.f);

    int j0 = beg;
    for (; j0 + 8 <= end; j0 += 8) {
        u32 pv[8];
#pragma unroll
        for (int j = 0; j < 8; ++j) pv[j] = csr[j0 + j];      // uniform -> s_load
        u32 q[8];
#pragma unroll
        for (int j = 0; j < 8; ++j) q[j] = xb[(size_t)(pv[j] & 0xffffu) * 128];
#pragma unroll
        for (int j = 0; j < 8; ++j) {
            float nm = __half2float(__ushort_as_half((u16)(pv[j] >> 16)));
            acc.x = fmaf(__uint_as_float(q[j] << 16), nm, acc.x);
            acc.y = fmaf(__uint_as_float(q[j] & 0xffff0000u), nm, acc.y);
        }
    }
    for (; j0 < end; ++j0) {
        u32 pv = csr[j0];
        float nm = __half2float(__ushort_as_half((u16)(pv >> 16)));
        u32 v = xb[(size_t)(pv & 0xffffu) * 128];
        acc.x = fmaf(__uint_as_float(v << 16), nm, acc.x);
        acc.y = fmaf(__uint_as_float(v & 0xffff0000u), nm, acc.y);
    }

    float2 bv = *(const float2*)(bias + lane * 2);
    acc.x += bv.x; acc.y += bv.y;
    *(float2*)(out + ((size_t)b * N + node) * 128 + lane * 2) = acc;
}

extern "C" void kernel_launch(void* const* d_in, const int* in_sizes, int n_in,
                              void* d_out, int out_size, void* d_ws, size_t ws_size,
                              hipStream_t stream) {
    const float* x    = (const float*)d_in[0];
    const int*   eidx = (const int*)d_in[1];   // [2][E] flat: src then dst
    const float* ew   = (const float*)d_in[2];
    const float* W    = (const float*)d_in[3];
    const float* bias = (const float*)d_in[4];
    float* out = (float*)d_out;

    const int E = in_sizes[2];                 // edge_weight count
    const int N = in_sizes[0] / 256;           // B=2, F=128 -> N = size/(2*128)
    const int nb = (N + 1023) / 1024;          // scan blocks (must be <= 256)

    const int* src = eidx;
    const int* dst = eidx + E;

    // ws footprint ~29 MB — below round-3-proven envelope. DO NOT GROW (round-6 overflow).
    char* w = (char*)d_ws;
    int*   deg    = (int*)w;   w += WS_ALIGN((size_t)N * 4);
    int*   rowptr = (int*)w;   w += WS_ALIGN((size_t)(N + 1) * 4);
    int*   cursor = (int*)w;   w += WS_ALIGN((size_t)N * 4);
    float* dis    = (float*)w; w += WS_ALIGN((size_t)N * 4);
    int*   bsum   = (int*)w;   w += WS_ALIGN((size_t)nb * 4);
    u32*   csr    = (u32*)w;   w += WS_ALIGN((size_t)E * 4);        // packed 4B/edge
    u16*   yh     = (u16*)w;   w += WS_ALIGN((size_t)N * 512);      // [N][2][128] bf16
    uint2* Wh     = (uint2*)w; w += WS_ALIGN((size_t)128 * 128 * 2);

    int pgrid = (N > 4096 ? N : 4096);
    hipLaunchKernelGGL(prep_kernel, dim3((pgrid + 255) / 256), dim3(256), 0, stream,
                       W, Wh, deg, N);
    int gpb = ((N + 31) / 32 + 3) / 4;                    // gemm blocks per batch
    int degBlocks = ((E + 3) / 4 + 255) / 256;
    hipLaunchKernelGGL(front_kernel, dim3(2 * gpb + degBlocks), dim3(256), 0, stream,
                       x, (const u16*)Wh, dst, deg, yh, N, E, gpb);
    hipLaunchKernelGGL(scan1_kernel, dim3(nb), dim3(256), 0, stream, deg, bsum, N);
    hipLaunchKernelGGL(scan3_kernel, dim3(nb), dim3(256), 0, stream, deg, bsum, rowptr, cursor, dis, N, nb);
    hipLaunchKernelGGL(fill_kernel, dim3(((E + 3) / 4 + 255) / 256), dim3(256), 0, stream,
                       src, dst, ew, dis, cursor, csr, E);
    hipLaunchKernelGGL(agg_kernel,  dim3(N, 2), dim3(64), 0, stream,
                       (const u32*)yh, rowptr, csr, bias, out, N);
}